// Round 2
// baseline (1848.728 us; speedup 1.0000x reference)
//
#include <hip/hip_runtime.h>
#include <math.h>

#define DEV __device__ __forceinline__

DEV float gelu_f(float x) { return 0.5f * x * (1.f + erff(x * 0.70710678118654752f)); }

// ---------------- zero fill ----------------
__global__ void fill_zero(float* __restrict__ p, long n) {
  long i = (long)blockIdx.x * blockDim.x + threadIdx.x;
  long st = (long)gridDim.x * blockDim.x;
  for (; i < n; i += st) p[i] = 0.f;
}

// ---------------- CSR build: histogram ----------------
__global__ void hist_k(const int* __restrict__ key, int n, int* __restrict__ cnt) {
  int i = blockIdx.x * blockDim.x + threadIdx.x;
  int st = gridDim.x * blockDim.x;
  for (; i < n; i += st) atomicAdd(&cnt[key[i]], 1);
}

// ---------------- CSR build: 4-graph exclusive scan (block b scans graph b) ----------------
__global__ __launch_bounds__(256) void scan4_k(
    int* c0, int* c1, int* c2, int* c3,
    int* r0, int* r1, int* r2, int* r3,
    int n0, int n1, int n2, int n3)
{
  int b = blockIdx.x;
  int* cnt = b == 0 ? c0 : b == 1 ? c1 : b == 2 ? c2 : c3;
  int* rp  = b == 0 ? r0 : b == 1 ? r1 : b == 2 ? r2 : r3;
  int nb   = b == 0 ? n0 : b == 1 ? n1 : b == 2 ? n2 : n3;
  __shared__ int ts[256];
  int tid = threadIdx.x;
  int chunk = (nb + 255) / 256;
  int lo = tid * chunk, hi = min(lo + chunk, nb);
  int s = 0;
  for (int i = lo; i < hi; ++i) s += cnt[i];
  ts[tid] = s;
  __syncthreads();
  for (int d = 1; d < 256; d <<= 1) {
    int v = (tid >= d) ? ts[tid - d] : 0;
    __syncthreads();
    ts[tid] += v;
    __syncthreads();
  }
  int run = (tid == 0) ? 0 : ts[tid - 1];
  for (int i = lo; i < hi; ++i) {
    int c = cnt[i];
    rp[i] = run;
    cnt[i] = run;   // cnt becomes the scatter cursor
    run += c;
  }
  if (tid == 0) rp[nb] = ts[255];
}

// ---------------- CSR build: scatter edge ids ----------------
__global__ void scat_k(const int* __restrict__ key, int n,
                       int* __restrict__ cursor, int* __restrict__ eids) {
  int i = blockIdx.x * blockDim.x + threadIdx.x;
  int st = gridDim.x * blockDim.x;
  for (; i < n; i += st) {
    int p = atomicAdd(&cursor[key[i]], 1);
    eids[p] = i;
  }
}

// ---------------- compose We' = attr1_W @ We[l], be' = attr1_b @ We[l] ----------------
__global__ __launch_bounds__(256) void compose_we(
    const float* __restrict__ a1W, const float* __restrict__ a1b,
    const float* __restrict__ c1We, const float* __restrict__ c2We,
    float* __restrict__ WEC, float* __restrict__ BEC)
{
  int l = blockIdx.x;
  const float* We = (l < 3) ? (c1We + l * 4096) : (c2We + (l - 3) * 4096);
  __shared__ float wes[4096];
  int tid = threadIdx.x;
  for (int i = tid; i < 4096; i += 256) wes[i] = We[i];
  __syncthreads();
  for (int i = tid; i < 1024; i += 256) {
    int k = i >> 6, j = i & 63;
    float s = 0.f;
    #pragma unroll 16
    for (int m = 0; m < 64; ++m) s += a1W[k * 64 + m] * wes[m * 64 + j];
    WEC[l * 1024 + i] = s;
  }
  if (tid < 64) {
    float s = 0.f;
    for (int m = 0; m < 64; ++m) s += a1b[m] * wes[m * 64 + tid];
    BEC[l * 64 + tid] = s;
  }
}

// ---------------- tiled GEMM: O = act(X@W + b), 64 output cols, optional second W ----------------
template <int ACT, bool PAIR>
__global__ __launch_bounds__(256) void gemm_tile(
    const float* __restrict__ X, int nrows, int K,
    const float* __restrict__ W1, const float* __restrict__ b1, float* __restrict__ O1,
    const float* __restrict__ W2, const float* __restrict__ b2, float* __restrict__ O2)
{
  __shared__ float xs[64][68];
  __shared__ float ws1[64][68];
  __shared__ float ws2[PAIR ? 64 : 1][68];
  const int tid = threadIdx.x;
  const int row0 = blockIdx.x * 64;
  const int tr = tid >> 4;
  const int tc = tid & 15;
  float acc1[4][4] = {{0.f,0.f,0.f,0.f},{0.f,0.f,0.f,0.f},{0.f,0.f,0.f,0.f},{0.f,0.f,0.f,0.f}};
  float acc2[4][4] = {{0.f,0.f,0.f,0.f},{0.f,0.f,0.f,0.f},{0.f,0.f,0.f,0.f},{0.f,0.f,0.f,0.f}};

  for (int kc = 0; kc < K; kc += 64) {
    const int klen = min(64, K - kc);
    __syncthreads();
    for (int i = tid; i < 4096; i += 256) {
      int r = i >> 6, c = i & 63;
      int gr = row0 + r;
      float v = 0.f;
      if (gr < nrows && c < klen) v = X[(size_t)gr * K + kc + c];
      xs[r][c] = v;
      float w1v = 0.f, w2v = 0.f;
      if (r < klen) {
        w1v = W1[(size_t)(kc + r) * 64 + c];
        if (PAIR) w2v = W2[(size_t)(kc + r) * 64 + c];
      }
      ws1[r][c] = w1v;
      if (PAIR) ws2[r][c] = w2v;
    }
    __syncthreads();
    #pragma unroll 8
    for (int k = 0; k < 64; ++k) {
      float xv[4];
      #pragma unroll
      for (int i = 0; i < 4; ++i) xv[i] = xs[tr * 4 + i][k];
      float4 w1 = *(const float4*)&ws1[k][tc * 4];
      #pragma unroll
      for (int i = 0; i < 4; ++i) {
        acc1[i][0] += xv[i] * w1.x; acc1[i][1] += xv[i] * w1.y;
        acc1[i][2] += xv[i] * w1.z; acc1[i][3] += xv[i] * w1.w;
      }
      if (PAIR) {
        float4 w2 = *(const float4*)&ws2[k][tc * 4];
        #pragma unroll
        for (int i = 0; i < 4; ++i) {
          acc2[i][0] += xv[i] * w2.x; acc2[i][1] += xv[i] * w2.y;
          acc2[i][2] += xv[i] * w2.z; acc2[i][3] += xv[i] * w2.w;
        }
      }
    }
  }

  float4 bv1 = *(const float4*)&b1[tc * 4];
  float4 bv2 = bv1;
  if (PAIR) bv2 = *(const float4*)&b2[tc * 4];
  #pragma unroll
  for (int i = 0; i < 4; ++i) {
    int gr = row0 + tr * 4 + i;
    if (gr >= nrows) continue;
    float4 o;
    o.x = acc1[i][0] + bv1.x; o.y = acc1[i][1] + bv1.y;
    o.z = acc1[i][2] + bv1.z; o.w = acc1[i][3] + bv1.w;
    if (ACT == 1) { o.x = gelu_f(o.x); o.y = gelu_f(o.y); o.z = gelu_f(o.z); o.w = gelu_f(o.w); }
    *(float4*)&O1[(size_t)gr * 64 + tc * 4] = o;
    if (PAIR) {
      float4 p;
      p.x = acc2[i][0] + bv2.x; p.y = acc2[i][1] + bv2.y;
      p.z = acc2[i][2] + bv2.z; p.w = acc2[i][3] + bv2.w;
      *(float4*)&O2[(size_t)gr * 64 + tc * 4] = p;
    }
  }
}

// ---------------- fused gather GATv2 layer (node graphs) ----------------
// wave per dst node: walk in-edges via CSR, register-accumulate softmax num/den,
// finalize (divide, bias, gelu, residual) in the same kernel. No atomics.
__global__ __launch_bounds__(256) void gat_gather(
    const int* __restrict__ rowptr, const int* __restrict__ eids,
    const int* __restrict__ esrc,
    const float* __restrict__ attr,
    const float* __restrict__ wec, const float* __restrict__ bec,
    const float* __restrict__ att, const float* __restrict__ bias,
    const float* __restrict__ xl, const float* __restrict__ xr,
    const float* __restrict__ pre, float* __restrict__ out, int n)
{
  __shared__ float wecs[1024];
  __shared__ float becs[64], atts[64], bs[64];
  int tid = threadIdx.x;
  for (int i = tid; i < 1024; i += 256) wecs[i] = wec[i];
  if (tid < 64) { becs[tid] = bec[tid]; atts[tid] = att[tid]; bs[tid] = bias[tid]; }
  __syncthreads();
  int wid = tid >> 6, lane = tid & 63;
  int d = blockIdx.x * 4 + wid;
  if (d >= n) return;
  float xrv = xr[(size_t)d * 64 + lane];
  float accn = 0.f, accd = 0.f;
  int j1 = rowptr[d + 1];
  for (int j = rowptr[d]; j < j1; ++j) {
    int e = eids[j];
    int s = esrc[e];
    float al = attr[(size_t)e * 16 + (lane & 15)];
    float ep = becs[lane];
    #pragma unroll
    for (int k = 0; k < 16; ++k)
      ep += __shfl(al, k, 64) * wecs[k * 64 + lane];
    float xlv = xl[(size_t)s * 64 + lane];
    float m = xlv + xrv + ep;
    float lr = m < 0.f ? 0.2f * m : m;
    float t = atts[lane] * lr;
    #pragma unroll
    for (int o = 32; o; o >>= 1) t += __shfl_xor(t, o, 64);
    float ex = expf(t);
    accn += ex * xlv;
    accd += ex;
  }
  float v = accn / (accd + 1e-16f) + bs[lane];
  float g = gelu_f(v);
  out[(size_t)d * 64 + lane] = pre ? (g + pre[(size_t)d * 64 + lane]) : g;
}

// ---------------- fused gather GATv2 (segment graph, edge_dim=1) ----------------
__global__ __launch_bounds__(256) void gat_seg_g(
    const int* __restrict__ rowptr, const int* __restrict__ eids,
    const int* __restrict__ ssrc, const float* __restrict__ vals,
    const float* __restrict__ we3, const float* __restrict__ att,
    const float* __restrict__ bias,
    const float* __restrict__ xl, const float* __restrict__ xr,
    float* __restrict__ out, int n)
{
  __shared__ float we3s[64], atts[64], bs[64];
  int tid = threadIdx.x;
  if (tid < 64) { we3s[tid] = we3[tid]; atts[tid] = att[tid]; bs[tid] = bias[tid]; }
  __syncthreads();
  int wid = tid >> 6, lane = tid & 63;
  int d = blockIdx.x * 4 + wid;
  if (d >= n) return;
  float xrv = xr[(size_t)d * 64 + lane];
  float accn = 0.f, accd = 0.f;
  int j1 = rowptr[d + 1];
  for (int j = rowptr[d]; j < j1; ++j) {
    int e = eids[j];
    int s = ssrc[e];
    float ep = vals[e] * we3s[lane];
    float xlv = xl[(size_t)s * 64 + lane];
    float m = xlv + xrv + ep;
    float lr = m < 0.f ? 0.2f * m : m;
    float t = atts[lane] * lr;
    #pragma unroll
    for (int o = 32; o; o >>= 1) t += __shfl_xor(t, o, 64);
    float ex = expf(t);
    accn += ex * xlv;
    accd += ex;
  }
  float v = accn / (accd + 1e-16f) + bs[lane];
  out[(size_t)d * 64 + lane] = gelu_f(v);
}

// ---------------- xf partial init: cols [0,64) seg_embed, [320,384) t, [384,448) w ----------------
__global__ void xf_init(
    float* __restrict__ xf, const float* __restrict__ seg_embed,
    const float* __restrict__ time_embed, const float* __restrict__ week_embed,
    const int* __restrict__ cur_t, const int* __restrict__ cur_w, int S)
{
  long idx = (long)blockIdx.x * blockDim.x + threadIdx.x;
  if (idx >= (long)S * 192) return;
  int s = idx / 192, c = idx % 192;
  if (c < 64)       xf[(size_t)s * 448 + c]         = seg_embed[(size_t)s * 64 + c];
  else if (c < 128) xf[(size_t)s * 448 + 256 + c]   = time_embed[cur_t[0] * 64 + (c - 64)];   // 320+(c-64)
  else              xf[(size_t)s * 448 + 256 + c]   = week_embed[cur_w[0] * 64 + (c - 128)];  // 384+(c-128)
}

// ---------------- gather spmm se: x1e + linearized x2e into xf cols [64,192) ----------------
// x2e = spmm(se,attr)@W2 + rowsum(se)*b2
__global__ __launch_bounds__(256) void spmm_se_g(
    const int* __restrict__ rowptr, const int* __restrict__ eids,
    const int* __restrict__ secol, const float* __restrict__ seval,
    const float* __restrict__ edge_embed, const float* __restrict__ attr,
    const float* __restrict__ W2, const float* __restrict__ b2,
    float* __restrict__ xf, int S)
{
  __shared__ float ws[1024];
  __shared__ float bs[64];
  int tid = threadIdx.x;
  for (int i = tid; i < 1024; i += 256) ws[i] = W2[i];
  if (tid < 64) bs[tid] = b2[tid];
  __syncthreads();
  int wid = tid >> 6, lane = tid & 63;
  int s = blockIdx.x * 4 + wid;
  if (s >= S) return;
  float acc1 = 0.f, aat = 0.f, vs = 0.f;
  int j1 = rowptr[s + 1];
  for (int j = rowptr[s]; j < j1; ++j) {
    int e = eids[j];
    int c = secol[e];
    float v = seval[e];
    acc1 += v * edge_embed[(size_t)c * 64 + lane];
    aat  += v * attr[(size_t)c * 16 + (lane & 15)];
    vs   += v;
  }
  float x2 = vs * bs[lane];
  #pragma unroll
  for (int k = 0; k < 16; ++k)
    x2 += __shfl(aat, k, 64) * ws[k * 64 + lane];
  xf[(size_t)s * 448 + 64 + lane]  = acc1;
  xf[(size_t)s * 448 + 128 + lane] = x2;
}

// ---------------- gather spmm sn: x1n (h) + x2n (nf) into xf cols [192,320) ----------------
__global__ __launch_bounds__(256) void spmm_sn_g(
    const int* __restrict__ rowptr, const int* __restrict__ eids,
    const int* __restrict__ sncol, const float* __restrict__ snval,
    const float* __restrict__ h, const float* __restrict__ nf,
    float* __restrict__ xf, int S)
{
  int tid = threadIdx.x;
  int wid = tid >> 6, lane = tid & 63;
  int s = blockIdx.x * 4 + wid;
  if (s >= S) return;
  float acch = 0.f, accf = 0.f;
  int j1 = rowptr[s + 1];
  for (int j = rowptr[s]; j < j1; ++j) {
    int e = eids[j];
    int c = sncol[e];
    float v = snval[e];
    acch += v * h[(size_t)c * 64 + lane];
    accf += v * nf[(size_t)c * 64 + lane];
  }
  xf[(size_t)s * 448 + 192 + lane] = acch;
  xf[(size_t)s * 448 + 256 + lane] = accf;
}

// ---------------- head: out = sigmoid([y2|xfg]@outW + b)*3600 ----------------
__global__ __launch_bounds__(256) void head_k(
    const float* __restrict__ y2, const float* __restrict__ xfg,
    const float* __restrict__ outW, const float* __restrict__ outb,
    float* __restrict__ out, int S)
{
  int wid = threadIdx.x >> 6, lane = threadIdx.x & 63;
  int s = blockIdx.x * 4 + wid;
  if (s >= S) return;
  float t = y2[(size_t)s * 64 + lane] * outW[lane] + xfg[(size_t)s * 64 + lane] * outW[64 + lane];
  #pragma unroll
  for (int o = 32; o; o >>= 1) t += __shfl_xor(t, o, 64);
  if (lane == 0) {
    float z = t + outb[0];
    out[s] = 3600.f / (1.f + expf(-z));
  }
}

extern "C" void kernel_launch(void* const* d_in, const int* in_sizes, int n_in,
                              void* d_out, int out_size, void* d_ws, size_t ws_size,
                              hipStream_t stream)
{
  const float* x_rec       = (const float*)d_in[0];
  const float* attr        = (const float*)d_in[1];
  const float* se_val      = (const float*)d_in[2];
  const float* sn_val      = (const float*)d_in[3];
  const float* ss_val      = (const float*)d_in[4];
  const float* node_embed  = (const float*)d_in[5];
  const float* edge_embed  = (const float*)d_in[6];
  const float* seg_embed   = (const float*)d_in[7];
  const float* time_embed  = (const float*)d_in[8];
  const float* week_embed  = (const float*)d_in[9];
  const float* node_lin_W  = (const float*)d_in[10];
  const float* node_lin_b  = (const float*)d_in[11];
  const float* attr1_W     = (const float*)d_in[12];
  const float* attr1_b     = (const float*)d_in[13];
  const float* attr2_W     = (const float*)d_in[14];
  const float* attr2_b     = (const float*)d_in[15];
  const float* c1_Wl       = (const float*)d_in[16];
  const float* c1_bl       = (const float*)d_in[17];
  const float* c1_Wr       = (const float*)d_in[18];
  const float* c1_br       = (const float*)d_in[19];
  const float* c1_att      = (const float*)d_in[21];
  const float* c1_bias     = (const float*)d_in[22];
  const float* c2_Wl       = (const float*)d_in[23];
  const float* c2_bl       = (const float*)d_in[24];
  const float* c2_Wr       = (const float*)d_in[25];
  const float* c2_br       = (const float*)d_in[26];
  const float* c2_att      = (const float*)d_in[28];
  const float* c2_bias     = (const float*)d_in[29];
  const float* c3_Wl       = (const float*)d_in[30];
  const float* c3_bl       = (const float*)d_in[31];
  const float* c3_Wr       = (const float*)d_in[32];
  const float* c3_br       = (const float*)d_in[33];
  const float* c3_We       = (const float*)d_in[34];
  const float* c3_att      = (const float*)d_in[35];
  const float* c3_bias     = (const float*)d_in[36];
  const float* lin1_W      = (const float*)d_in[37];
  const float* lin1_b      = (const float*)d_in[38];
  const float* lin2_W      = (const float*)d_in[39];
  const float* lin2_b      = (const float*)d_in[40];
  const float* out_W       = (const float*)d_in[41];
  const float* out_b       = (const float*)d_in[42];
  const int* edge_index    = (const int*)d_in[43];
  const int* se_row        = (const int*)d_in[44];
  const int* se_col        = (const int*)d_in[45];
  const int* sn_row        = (const int*)d_in[46];
  const int* sn_col        = (const int*)d_in[47];
  const int* ss_row        = (const int*)d_in[48];
  const int* ss_col        = (const int*)d_in[49];
  const int* cur_t         = (const int*)d_in[50];
  const int* cur_w         = (const int*)d_in[51];

  const int N = in_sizes[0] / 32;
  const int E = in_sizes[1] / 16;
  const int S = in_sizes[7] / 64;
  const int NNZSS = in_sizes[4];

  // workspace layout
  float* W = (float*)d_ws;
  size_t o = 0;
  float* A   = W + o; o += (size_t)N * 64;   // xl / xl3
  float* B   = W + o; o += (size_t)N * 64;   // xr / xr3
  float* Hc  = W + o; o += (size_t)N * 64;   // conv1 state / final h
  float* F0  = W + o; o += (size_t)N * 64;   // nf0 (conv2 pre)
  float* Fc  = W + o; o += (size_t)N * 64;   // conv2 state / final nf
  float* XF  = W + o; o += (size_t)S * 448;  // xf [S,448]
  float* XFG = W + o; o += (size_t)S * 64;
  float* Y   = W + o; o += (size_t)S * 64;
  float* Y2  = W + o; o += (size_t)S * 64;
  float* WEC = W + o; o += 6 * 1024;
  float* BEC = W + o; o += 6 * 64;
  // CSR arrays (ints)
  int* I = (int*)(W + o);
  size_t q = 0;
  int* cur1 = I + q; q += N + 1;   // cursors double as histogram counters
  int* cur2 = I + q; q += S + 1;
  int* cur3 = I + q; q += S + 1;
  int* cur4 = I + q; q += S + 1;
  int* rp1  = I + q; q += N + 1;
  int* rp2  = I + q; q += S + 1;
  int* rp3  = I + q; q += S + 1;
  int* rp4  = I + q; q += S + 1;
  int* eid1 = I + q; q += E;
  int* eid2 = I + q; q += E;
  int* eid3 = I + q; q += E;
  int* eid4 = I + q; q += NNZSS;

  const int* edst = edge_index + E;  // edge_index row 1

  dim3 blk(256);
  const int gN64 = (N + 63) / 64;
  const int gS64 = (S + 63) / 64;
  const int gN4  = (N + 3) / 4;
  const int gS4  = (S + 3) / 4;

  // ---- CSR builds (cursors zeroed first; 0 bits == 0.f) ----
  long ztot = (long)(N + 1) + 3L * (S + 1);
  fill_zero<<<256, blk, 0, stream>>>((float*)cur1, ztot);
  hist_k<<<512, blk, 0, stream>>>(edst,   E,     cur1);
  hist_k<<<512, blk, 0, stream>>>(se_row, E,     cur2);
  hist_k<<<512, blk, 0, stream>>>(sn_row, E,     cur3);
  hist_k<<<512, blk, 0, stream>>>(ss_col, NNZSS, cur4);
  scan4_k<<<4, blk, 0, stream>>>(cur1, cur2, cur3, cur4, rp1, rp2, rp3, rp4, N, S, S, S);
  scat_k<<<512, blk, 0, stream>>>(edst,   E,     cur1, eid1);
  scat_k<<<512, blk, 0, stream>>>(se_row, E,     cur2, eid2);
  scat_k<<<512, blk, 0, stream>>>(sn_row, E,     cur3, eid3);
  scat_k<<<512, blk, 0, stream>>>(ss_col, NNZSS, cur4, eid4);

  // composed edge-projection weights
  compose_we<<<6, blk, 0, stream>>>(attr1_W, attr1_b,
                                    (const float*)d_in[20], (const float*)d_in[27], WEC, BEC);

  // nf0 = gelu(x_rec @ node_lin_W + b)   (K=32)
  gemm_tile<1, false><<<gN64, blk, 0, stream>>>(x_rec, N, 32, node_lin_W, node_lin_b, F0,
                                                nullptr, nullptr, nullptr);

  // conv1 stack (pre = node_embed)
  const float* state = node_embed;
  for (int l = 0; l < 3; ++l) {
    gemm_tile<0, true><<<gN64, blk, 0, stream>>>(state, N, 64,
        c1_Wl + l * 4096, c1_bl + l * 64, A, c1_Wr + l * 4096, c1_br + l * 64, B);
    gat_gather<<<gN4, blk, 0, stream>>>(rp1, eid1, edge_index, attr,
        WEC + l * 1024, BEC + l * 64, c1_att + l * 64, c1_bias + l * 64,
        A, B, node_embed, Hc, N);
    state = Hc;
  }

  // conv2 stack (pre = F0)
  state = F0;
  for (int l = 0; l < 3; ++l) {
    gemm_tile<0, true><<<gN64, blk, 0, stream>>>(state, N, 64,
        c2_Wl + l * 4096, c2_bl + l * 64, A, c2_Wr + l * 4096, c2_br + l * 64, B);
    gat_gather<<<gN4, blk, 0, stream>>>(rp1, eid1, edge_index, attr,
        WEC + (3 + l) * 1024, BEC + (3 + l) * 64, c2_att + l * 64, c2_bias + l * 64,
        A, B, F0, Fc, N);
    state = Fc;
  }

  // xf assembly
  xf_init<<<((long)S * 192 + 255) / 256, blk, 0, stream>>>(XF, seg_embed, time_embed, week_embed,
                                                           cur_t, cur_w, S);
  spmm_se_g<<<gS4, blk, 0, stream>>>(rp2, eid2, se_col, se_val, edge_embed, attr,
                                     attr2_W, attr2_b, XF, S);
  spmm_sn_g<<<gS4, blk, 0, stream>>>(rp3, eid3, sn_col, sn_val, Hc, Fc, XF, S);

  // conv3 on segment graph (K=448)
  gemm_tile<0, true><<<gS64, blk, 0, stream>>>(XF, S, 448, c3_Wl, c3_bl, A, c3_Wr, c3_br, B);
  gat_seg_g<<<gS4, blk, 0, stream>>>(rp4, eid4, ss_row, ss_val, c3_We, c3_att, c3_bias,
                                     A, B, XFG, S);

  // MLP head
  gemm_tile<1, false><<<gS64, blk, 0, stream>>>(XF, S, 448, lin1_W, lin1_b, Y,
                                                nullptr, nullptr, nullptr);
  gemm_tile<1, false><<<gS64, blk, 0, stream>>>(Y, S, 64, lin2_W, lin2_b, Y2,
                                                nullptr, nullptr, nullptr);
  head_k<<<gS4, blk, 0, stream>>>(Y2, XFG, out_W, out_b, (float*)d_out, S);
}

// Round 3
// 1667.188 us; speedup vs baseline: 1.1089x; 1.1089x over previous
//
#include <hip/hip_runtime.h>
#include <math.h>

#define DEV __device__ __forceinline__

DEV float gelu_f(float x) { return 0.5f * x * (1.f + erff(x * 0.70710678118654752f)); }

// ---------------- zero fill ----------------
__global__ void fill_zero(float* __restrict__ p, long n) {
  long i = (long)blockIdx.x * blockDim.x + threadIdx.x;
  long st = (long)gridDim.x * blockDim.x;
  for (; i < n; i += st) p[i] = 0.f;
}

// ---------------- CSR build: histogram ----------------
__global__ void hist_k(const int* __restrict__ key, int n, int* __restrict__ cnt) {
  int i = blockIdx.x * blockDim.x + threadIdx.x;
  int st = gridDim.x * blockDim.x;
  for (; i < n; i += st) atomicAdd(&cnt[key[i]], 1);
}

// ---------------- multi-block exclusive scan (3 passes, 1024 elems/block) ----------------
__global__ __launch_bounds__(256) void scan_p1(const int* __restrict__ cnt, int n,
                                               int* __restrict__ bsum) {
  __shared__ int ts[256];
  int base = blockIdx.x * 1024;
  int s = 0;
  #pragma unroll
  for (int k = 0; k < 4; ++k) {
    int g = base + threadIdx.x * 4 + k;
    if (g < n) s += cnt[g];
  }
  ts[threadIdx.x] = s;
  __syncthreads();
  for (int d = 128; d; d >>= 1) {
    if (threadIdx.x < d) ts[threadIdx.x] += ts[threadIdx.x + d];
    __syncthreads();
  }
  if (threadIdx.x == 0) bsum[blockIdx.x] = ts[0];
}

__global__ __launch_bounds__(256) void scan_p2(int* __restrict__ bsum, int nb,
                                               int* __restrict__ rp, int n) {
  __shared__ int ts[256];
  int tid = threadIdx.x;
  int v = (tid < nb) ? bsum[tid] : 0;
  ts[tid] = v;
  __syncthreads();
  for (int d = 1; d < 256; d <<= 1) {
    int w = (tid >= d) ? ts[tid - d] : 0;
    __syncthreads();
    ts[tid] += w;
    __syncthreads();
  }
  // exclusive
  if (tid < nb) bsum[tid] = (tid == 0) ? 0 : ts[tid - 1];
  if (tid == 255) rp[n] = ts[255];
}

__global__ __launch_bounds__(256) void scan_p3(const int* __restrict__ cnt, int n,
                                               const int* __restrict__ bsum,
                                               int* __restrict__ rp, int* __restrict__ cursor) {
  __shared__ int ts[256];
  int base = blockIdx.x * 1024;
  int tid = threadIdx.x;
  int c[4];
  int s = 0;
  #pragma unroll
  for (int k = 0; k < 4; ++k) {
    int g = base + tid * 4 + k;
    c[k] = (g < n) ? cnt[g] : 0;
    s += c[k];
  }
  ts[tid] = s;
  __syncthreads();
  for (int d = 1; d < 256; d <<= 1) {
    int w = (tid >= d) ? ts[tid - d] : 0;
    __syncthreads();
    ts[tid] += w;
    __syncthreads();
  }
  int run = bsum[blockIdx.x] + ((tid == 0) ? 0 : ts[tid - 1]);
  #pragma unroll
  for (int k = 0; k < 4; ++k) {
    int g = base + tid * 4 + k;
    if (g < n) {
      rp[g] = run;
      cursor[g] = run;
      run += c[k];
    }
  }
}

// ---------------- CSR build: scatter edge ids ----------------
__global__ void scat_k(const int* __restrict__ key, int n,
                       int* __restrict__ cursor, int* __restrict__ eids) {
  int i = blockIdx.x * blockDim.x + threadIdx.x;
  int st = gridDim.x * blockDim.x;
  for (; i < n; i += st) {
    int p = atomicAdd(&cursor[key[i]], 1);
    eids[p] = i;
  }
}

// ---------------- compose We' = attr1_W @ We[l], be' = attr1_b @ We[l] ----------------
__global__ __launch_bounds__(256) void compose_we(
    const float* __restrict__ a1W, const float* __restrict__ a1b,
    const float* __restrict__ c1We, const float* __restrict__ c2We,
    float* __restrict__ WEC, float* __restrict__ BEC)
{
  int l = blockIdx.x;
  const float* We = (l < 3) ? (c1We + l * 4096) : (c2We + (l - 3) * 4096);
  __shared__ float wes[4096];
  int tid = threadIdx.x;
  for (int i = tid; i < 4096; i += 256) wes[i] = We[i];
  __syncthreads();
  for (int i = tid; i < 1024; i += 256) {
    int k = i >> 6, j = i & 63;
    float s = 0.f;
    #pragma unroll 16
    for (int m = 0; m < 64; ++m) s += a1W[k * 64 + m] * wes[m * 64 + j];
    WEC[l * 1024 + i] = s;
  }
  if (tid < 64) {
    float s = 0.f;
    for (int m = 0; m < 64; ++m) s += a1b[m] * wes[m * 64 + tid];
    BEC[l * 64 + tid] = s;
  }
}

// ---------------- tiled GEMM: O = act(X@W + b), 64 output cols, optional second W ----------------
template <int ACT, bool PAIR>
__global__ __launch_bounds__(256) void gemm_tile(
    const float* __restrict__ X, int nrows, int K,
    const float* __restrict__ W1, const float* __restrict__ b1, float* __restrict__ O1,
    const float* __restrict__ W2, const float* __restrict__ b2, float* __restrict__ O2)
{
  __shared__ float xs[64][68];
  __shared__ float ws1[64][68];
  __shared__ float ws2[PAIR ? 64 : 1][68];
  const int tid = threadIdx.x;
  const int row0 = blockIdx.x * 64;
  const int tr = tid >> 4;
  const int tc = tid & 15;
  float acc1[4][4] = {{0.f,0.f,0.f,0.f},{0.f,0.f,0.f,0.f},{0.f,0.f,0.f,0.f},{0.f,0.f,0.f,0.f}};
  float acc2[4][4] = {{0.f,0.f,0.f,0.f},{0.f,0.f,0.f,0.f},{0.f,0.f,0.f,0.f},{0.f,0.f,0.f,0.f}};

  for (int kc = 0; kc < K; kc += 64) {
    const int klen = min(64, K - kc);
    __syncthreads();
    for (int i = tid; i < 4096; i += 256) {
      int r = i >> 6, c = i & 63;
      int gr = row0 + r;
      float v = 0.f;
      if (gr < nrows && c < klen) v = X[(size_t)gr * K + kc + c];
      xs[r][c] = v;
      float w1v = 0.f, w2v = 0.f;
      if (r < klen) {
        w1v = W1[(size_t)(kc + r) * 64 + c];
        if (PAIR) w2v = W2[(size_t)(kc + r) * 64 + c];
      }
      ws1[r][c] = w1v;
      if (PAIR) ws2[r][c] = w2v;
    }
    __syncthreads();
    #pragma unroll 8
    for (int k = 0; k < 64; ++k) {
      float xv[4];
      #pragma unroll
      for (int i = 0; i < 4; ++i) xv[i] = xs[tr * 4 + i][k];
      float4 w1 = *(const float4*)&ws1[k][tc * 4];
      #pragma unroll
      for (int i = 0; i < 4; ++i) {
        acc1[i][0] += xv[i] * w1.x; acc1[i][1] += xv[i] * w1.y;
        acc1[i][2] += xv[i] * w1.z; acc1[i][3] += xv[i] * w1.w;
      }
      if (PAIR) {
        float4 w2 = *(const float4*)&ws2[k][tc * 4];
        #pragma unroll
        for (int i = 0; i < 4; ++i) {
          acc2[i][0] += xv[i] * w2.x; acc2[i][1] += xv[i] * w2.y;
          acc2[i][2] += xv[i] * w2.z; acc2[i][3] += xv[i] * w2.w;
        }
      }
    }
  }

  float4 bv1 = *(const float4*)&b1[tc * 4];
  float4 bv2 = bv1;
  if (PAIR) bv2 = *(const float4*)&b2[tc * 4];
  #pragma unroll
  for (int i = 0; i < 4; ++i) {
    int gr = row0 + tr * 4 + i;
    if (gr >= nrows) continue;
    float4 o;
    o.x = acc1[i][0] + bv1.x; o.y = acc1[i][1] + bv1.y;
    o.z = acc1[i][2] + bv1.z; o.w = acc1[i][3] + bv1.w;
    if (ACT == 1) { o.x = gelu_f(o.x); o.y = gelu_f(o.y); o.z = gelu_f(o.z); o.w = gelu_f(o.w); }
    *(float4*)&O1[(size_t)gr * 64 + tc * 4] = o;
    if (PAIR) {
      float4 p;
      p.x = acc2[i][0] + bv2.x; p.y = acc2[i][1] + bv2.y;
      p.z = acc2[i][2] + bv2.z; p.w = acc2[i][3] + bv2.w;
      *(float4*)&O2[(size_t)gr * 64 + tc * 4] = p;
    }
  }
}

// ---------------- fused gather GATv2 layer (node graphs) ----------------
__global__ __launch_bounds__(256) void gat_gather(
    const int* __restrict__ rowptr, const int* __restrict__ eids,
    const int* __restrict__ esrc,
    const float* __restrict__ attr,
    const float* __restrict__ wec, const float* __restrict__ bec,
    const float* __restrict__ att, const float* __restrict__ bias,
    const float* __restrict__ xl, const float* __restrict__ xr,
    const float* __restrict__ pre, float* __restrict__ out, int n)
{
  __shared__ float wecs[1024];
  __shared__ float becs[64], atts[64], bs[64];
  int tid = threadIdx.x;
  for (int i = tid; i < 1024; i += 256) wecs[i] = wec[i];
  if (tid < 64) { becs[tid] = bec[tid]; atts[tid] = att[tid]; bs[tid] = bias[tid]; }
  __syncthreads();
  int wid = tid >> 6, lane = tid & 63;
  int d = blockIdx.x * 4 + wid;
  if (d >= n) return;
  float xrv = xr[(size_t)d * 64 + lane];
  float accn = 0.f, accd = 0.f;
  int j1 = rowptr[d + 1];
  for (int j = rowptr[d]; j < j1; ++j) {
    int e = eids[j];
    int s = esrc[e];
    float al = attr[(size_t)e * 16 + (lane & 15)];
    float ep = becs[lane];
    #pragma unroll
    for (int k = 0; k < 16; ++k)
      ep += __shfl(al, k, 64) * wecs[k * 64 + lane];
    float xlv = xl[(size_t)s * 64 + lane];
    float m = xlv + xrv + ep;
    float lr = m < 0.f ? 0.2f * m : m;
    float t = atts[lane] * lr;
    #pragma unroll
    for (int o = 32; o; o >>= 1) t += __shfl_xor(t, o, 64);
    float ex = expf(t);
    accn += ex * xlv;
    accd += ex;
  }
  float v = accn / (accd + 1e-16f) + bs[lane];
  float g = gelu_f(v);
  out[(size_t)d * 64 + lane] = pre ? (g + pre[(size_t)d * 64 + lane]) : g;
}

// ---------------- fused gather GATv2 (segment graph, edge_dim=1) ----------------
__global__ __launch_bounds__(256) void gat_seg_g(
    const int* __restrict__ rowptr, const int* __restrict__ eids,
    const int* __restrict__ ssrc, const float* __restrict__ vals,
    const float* __restrict__ we3, const float* __restrict__ att,
    const float* __restrict__ bias,
    const float* __restrict__ xl, const float* __restrict__ xr,
    float* __restrict__ out, int n)
{
  __shared__ float we3s[64], atts[64], bs[64];
  int tid = threadIdx.x;
  if (tid < 64) { we3s[tid] = we3[tid]; atts[tid] = att[tid]; bs[tid] = bias[tid]; }
  __syncthreads();
  int wid = tid >> 6, lane = tid & 63;
  int d = blockIdx.x * 4 + wid;
  if (d >= n) return;
  float xrv = xr[(size_t)d * 64 + lane];
  float accn = 0.f, accd = 0.f;
  int j1 = rowptr[d + 1];
  for (int j = rowptr[d]; j < j1; ++j) {
    int e = eids[j];
    int s = ssrc[e];
    float ep = vals[e] * we3s[lane];
    float xlv = xl[(size_t)s * 64 + lane];
    float m = xlv + xrv + ep;
    float lr = m < 0.f ? 0.2f * m : m;
    float t = atts[lane] * lr;
    #pragma unroll
    for (int o = 32; o; o >>= 1) t += __shfl_xor(t, o, 64);
    float ex = expf(t);
    accn += ex * xlv;
    accd += ex;
  }
  float v = accn / (accd + 1e-16f) + bs[lane];
  out[(size_t)d * 64 + lane] = gelu_f(v);
}

// ---------------- xf partial init ----------------
__global__ void xf_init(
    float* __restrict__ xf, const float* __restrict__ seg_embed,
    const float* __restrict__ time_embed, const float* __restrict__ week_embed,
    const int* __restrict__ cur_t, const int* __restrict__ cur_w, int S)
{
  long idx = (long)blockIdx.x * blockDim.x + threadIdx.x;
  if (idx >= (long)S * 192) return;
  int s = idx / 192, c = idx % 192;
  if (c < 64)       xf[(size_t)s * 448 + c]         = seg_embed[(size_t)s * 64 + c];
  else if (c < 128) xf[(size_t)s * 448 + 256 + c]   = time_embed[cur_t[0] * 64 + (c - 64)];
  else              xf[(size_t)s * 448 + 256 + c]   = week_embed[cur_w[0] * 64 + (c - 128)];
}

// ---------------- gather spmm se ----------------
__global__ __launch_bounds__(256) void spmm_se_g(
    const int* __restrict__ rowptr, const int* __restrict__ eids,
    const int* __restrict__ secol, const float* __restrict__ seval,
    const float* __restrict__ edge_embed, const float* __restrict__ attr,
    const float* __restrict__ W2, const float* __restrict__ b2,
    float* __restrict__ xf, int S)
{
  __shared__ float ws[1024];
  __shared__ float bs[64];
  int tid = threadIdx.x;
  for (int i = tid; i < 1024; i += 256) ws[i] = W2[i];
  if (tid < 64) bs[tid] = b2[tid];
  __syncthreads();
  int wid = tid >> 6, lane = tid & 63;
  int s = blockIdx.x * 4 + wid;
  if (s >= S) return;
  float acc1 = 0.f, aat = 0.f, vs = 0.f;
  int j1 = rowptr[s + 1];
  for (int j = rowptr[s]; j < j1; ++j) {
    int e = eids[j];
    int c = secol[e];
    float v = seval[e];
    acc1 += v * edge_embed[(size_t)c * 64 + lane];
    aat  += v * attr[(size_t)c * 16 + (lane & 15)];
    vs   += v;
  }
  float x2 = vs * bs[lane];
  #pragma unroll
  for (int k = 0; k < 16; ++k)
    x2 += __shfl(aat, k, 64) * ws[k * 64 + lane];
  xf[(size_t)s * 448 + 64 + lane]  = acc1;
  xf[(size_t)s * 448 + 128 + lane] = x2;
}

// ---------------- gather spmm sn ----------------
__global__ __launch_bounds__(256) void spmm_sn_g(
    const int* __restrict__ rowptr, const int* __restrict__ eids,
    const int* __restrict__ sncol, const float* __restrict__ snval,
    const float* __restrict__ h, const float* __restrict__ nf,
    float* __restrict__ xf, int S)
{
  int tid = threadIdx.x;
  int wid = tid >> 6, lane = tid & 63;
  int s = blockIdx.x * 4 + wid;
  if (s >= S) return;
  float acch = 0.f, accf = 0.f;
  int j1 = rowptr[s + 1];
  for (int j = rowptr[s]; j < j1; ++j) {
    int e = eids[j];
    int c = sncol[e];
    float v = snval[e];
    acch += v * h[(size_t)c * 64 + lane];
    accf += v * nf[(size_t)c * 64 + lane];
  }
  xf[(size_t)s * 448 + 192 + lane] = acch;
  xf[(size_t)s * 448 + 256 + lane] = accf;
}

// ---------------- head ----------------
__global__ __launch_bounds__(256) void head_k(
    const float* __restrict__ y2, const float* __restrict__ xfg,
    const float* __restrict__ outW, const float* __restrict__ outb,
    float* __restrict__ out, int S)
{
  int wid = threadIdx.x >> 6, lane = threadIdx.x & 63;
  int s = blockIdx.x * 4 + wid;
  if (s >= S) return;
  float t = y2[(size_t)s * 64 + lane] * outW[lane] + xfg[(size_t)s * 64 + lane] * outW[64 + lane];
  #pragma unroll
  for (int o = 32; o; o >>= 1) t += __shfl_xor(t, o, 64);
  if (lane == 0) {
    float z = t + outb[0];
    out[s] = 3600.f / (1.f + expf(-z));
  }
}

extern "C" void kernel_launch(void* const* d_in, const int* in_sizes, int n_in,
                              void* d_out, int out_size, void* d_ws, size_t ws_size,
                              hipStream_t stream)
{
  const float* x_rec       = (const float*)d_in[0];
  const float* attr        = (const float*)d_in[1];
  const float* se_val      = (const float*)d_in[2];
  const float* sn_val      = (const float*)d_in[3];
  const float* ss_val      = (const float*)d_in[4];
  const float* node_embed  = (const float*)d_in[5];
  const float* edge_embed  = (const float*)d_in[6];
  const float* seg_embed   = (const float*)d_in[7];
  const float* time_embed  = (const float*)d_in[8];
  const float* week_embed  = (const float*)d_in[9];
  const float* node_lin_W  = (const float*)d_in[10];
  const float* node_lin_b  = (const float*)d_in[11];
  const float* attr2_W     = (const float*)d_in[14];
  const float* attr2_b     = (const float*)d_in[15];
  const float* c1_Wl       = (const float*)d_in[16];
  const float* c1_bl       = (const float*)d_in[17];
  const float* c1_Wr       = (const float*)d_in[18];
  const float* c1_br       = (const float*)d_in[19];
  const float* c1_att      = (const float*)d_in[21];
  const float* c1_bias     = (const float*)d_in[22];
  const float* c2_Wl       = (const float*)d_in[23];
  const float* c2_bl       = (const float*)d_in[24];
  const float* c2_Wr       = (const float*)d_in[25];
  const float* c2_br       = (const float*)d_in[26];
  const float* c2_att      = (const float*)d_in[28];
  const float* c2_bias     = (const float*)d_in[29];
  const float* c3_Wl       = (const float*)d_in[30];
  const float* c3_bl       = (const float*)d_in[31];
  const float* c3_Wr       = (const float*)d_in[32];
  const float* c3_br       = (const float*)d_in[33];
  const float* c3_We       = (const float*)d_in[34];
  const float* c3_att      = (const float*)d_in[35];
  const float* c3_bias     = (const float*)d_in[36];
  const float* lin1_W      = (const float*)d_in[37];
  const float* lin1_b      = (const float*)d_in[38];
  const float* lin2_W      = (const float*)d_in[39];
  const float* lin2_b      = (const float*)d_in[40];
  const float* out_W       = (const float*)d_in[41];
  const float* out_b       = (const float*)d_in[42];
  const int* edge_index    = (const int*)d_in[43];
  const int* se_row        = (const int*)d_in[44];
  const int* se_col        = (const int*)d_in[45];
  const int* sn_row        = (const int*)d_in[46];
  const int* sn_col        = (const int*)d_in[47];
  const int* ss_row        = (const int*)d_in[48];
  const int* ss_col        = (const int*)d_in[49];
  const int* cur_t         = (const int*)d_in[50];
  const int* cur_w         = (const int*)d_in[51];

  const int N = in_sizes[0] / 32;
  const int E = in_sizes[1] / 16;
  const int S = in_sizes[7] / 64;
  const int NNZSS = in_sizes[4];

  // workspace layout
  float* W = (float*)d_ws;
  size_t o = 0;
  float* A   = W + o; o += (size_t)N * 64;   // xl / xl3
  float* B   = W + o; o += (size_t)N * 64;   // xr / xr3
  float* Hc  = W + o; o += (size_t)N * 64;   // conv1 state / final h
  float* F0  = W + o; o += (size_t)N * 64;   // nf0 (conv2 pre)
  float* Fc  = W + o; o += (size_t)N * 64;   // conv2 state / final nf
  float* XF  = W + o; o += (size_t)S * 448;  // xf [S,448]
  float* XFG = W + o; o += (size_t)S * 64;
  float* Y   = W + o; o += (size_t)S * 64;
  float* Y2  = W + o; o += (size_t)S * 64;
  float* WEC = W + o; o += 6 * 1024;
  float* BEC = W + o; o += 6 * 64;
  // CSR arrays (ints)
  int* I = (int*)(W + o);
  size_t q = 0;
  int* cur1 = I + q; q += N + 1;
  int* cur2 = I + q; q += S + 1;
  int* cur3 = I + q; q += S + 1;
  int* cur4 = I + q; q += S + 1;
  int* rp1  = I + q; q += N + 1;
  int* rp2  = I + q; q += S + 1;
  int* rp3  = I + q; q += S + 1;
  int* rp4  = I + q; q += S + 1;
  int* eid1 = I + q; q += E;
  int* eid2 = I + q; q += E;
  int* eid3 = I + q; q += E;
  int* eid4 = I + q; q += NNZSS;
  int* bs1  = I + q; q += 256;
  int* bs2  = I + q; q += 256;
  int* bs3  = I + q; q += 256;
  int* bs4  = I + q; q += 256;

  const int* edst = edge_index + E;

  dim3 blk(256);
  const int gN64 = (N + 63) / 64;
  const int gS64 = (S + 63) / 64;
  const int gN4  = (N + 3) / 4;
  const int gS4  = (S + 3) / 4;
  const int nbN  = (N + 1 + 1023) / 1024;
  const int nbS  = (S + 1 + 1023) / 1024;

  // ---- CSR builds ----
  long ztot = (long)(N + 1) + 3L * (S + 1);
  fill_zero<<<256, blk, 0, stream>>>((float*)cur1, ztot);
  hist_k<<<512, blk, 0, stream>>>(edst,   E,     cur1);
  hist_k<<<512, blk, 0, stream>>>(se_row, E,     cur2);
  hist_k<<<512, blk, 0, stream>>>(sn_row, E,     cur3);
  hist_k<<<512, blk, 0, stream>>>(ss_col, NNZSS, cur4);

  scan_p1<<<nbN, blk, 0, stream>>>(cur1, N + 1, bs1);
  scan_p1<<<nbS, blk, 0, stream>>>(cur2, S + 1, bs2);
  scan_p1<<<nbS, blk, 0, stream>>>(cur3, S + 1, bs3);
  scan_p1<<<nbS, blk, 0, stream>>>(cur4, S + 1, bs4);
  scan_p2<<<1, blk, 0, stream>>>(bs1, nbN, rp1, N);
  scan_p2<<<1, blk, 0, stream>>>(bs2, nbS, rp2, S);
  scan_p2<<<1, blk, 0, stream>>>(bs3, nbS, rp3, S);
  scan_p2<<<1, blk, 0, stream>>>(bs4, nbS, rp4, S);
  scan_p3<<<nbN, blk, 0, stream>>>(cur1, N, bs1, rp1, cur1);
  scan_p3<<<nbS, blk, 0, stream>>>(cur2, S, bs2, rp2, cur2);
  scan_p3<<<nbS, blk, 0, stream>>>(cur3, S, bs3, rp3, cur3);
  scan_p3<<<nbS, blk, 0, stream>>>(cur4, S, bs4, rp4, cur4);

  scat_k<<<512, blk, 0, stream>>>(edst,   E,     cur1, eid1);
  scat_k<<<512, blk, 0, stream>>>(se_row, E,     cur2, eid2);
  scat_k<<<512, blk, 0, stream>>>(sn_row, E,     cur3, eid3);
  scat_k<<<512, blk, 0, stream>>>(ss_col, NNZSS, cur4, eid4);

  // composed edge-projection weights
  compose_we<<<6, blk, 0, stream>>>((const float*)d_in[12], (const float*)d_in[13],
                                    (const float*)d_in[20], (const float*)d_in[27], WEC, BEC);

  // nf0 = gelu(x_rec @ node_lin_W + b)   (K=32)
  gemm_tile<1, false><<<gN64, blk, 0, stream>>>(x_rec, N, 32, node_lin_W, node_lin_b, F0,
                                                nullptr, nullptr, nullptr);

  // conv1 stack (pre = node_embed)
  const float* state = node_embed;
  for (int l = 0; l < 3; ++l) {
    gemm_tile<0, true><<<gN64, blk, 0, stream>>>(state, N, 64,
        c1_Wl + l * 4096, c1_bl + l * 64, A, c1_Wr + l * 4096, c1_br + l * 64, B);
    gat_gather<<<gN4, blk, 0, stream>>>(rp1, eid1, edge_index, attr,
        WEC + l * 1024, BEC + l * 64, c1_att + l * 64, c1_bias + l * 64,
        A, B, node_embed, Hc, N);
    state = Hc;
  }

  // conv2 stack (pre = F0)
  state = F0;
  for (int l = 0; l < 3; ++l) {
    gemm_tile<0, true><<<gN64, blk, 0, stream>>>(state, N, 64,
        c2_Wl + l * 4096, c2_bl + l * 64, A, c2_Wr + l * 4096, c2_br + l * 64, B);
    gat_gather<<<gN4, blk, 0, stream>>>(rp1, eid1, edge_index, attr,
        WEC + (3 + l) * 1024, BEC + (3 + l) * 64, c2_att + l * 64, c2_bias + l * 64,
        A, B, F0, Fc, N);
    state = Fc;
  }

  // xf assembly
  xf_init<<<((long)S * 192 + 255) / 256, blk, 0, stream>>>(XF, seg_embed, time_embed, week_embed,
                                                           cur_t, cur_w, S);
  spmm_se_g<<<gS4, blk, 0, stream>>>(rp2, eid2, se_col, se_val, edge_embed, attr,
                                     attr2_W, attr2_b, XF, S);
  spmm_sn_g<<<gS4, blk, 0, stream>>>(rp3, eid3, sn_col, sn_val, Hc, Fc, XF, S);

  // conv3 on segment graph (K=448)
  gemm_tile<0, true><<<gS64, blk, 0, stream>>>(XF, S, 448, c3_Wl, c3_bl, A, c3_Wr, c3_br, B);
  gat_seg_g<<<gS4, blk, 0, stream>>>(rp4, eid4, ss_row, ss_val, c3_We, c3_att, c3_bias,
                                     A, B, XFG, S);

  // MLP head
  gemm_tile<1, false><<<gS64, blk, 0, stream>>>(XF, S, 448, lin1_W, lin1_b, Y,
                                                nullptr, nullptr, nullptr);
  gemm_tile<1, false><<<gS64, blk, 0, stream>>>(Y, S, 64, lin2_W, lin2_b, Y2,
                                                nullptr, nullptr, nullptr);
  head_k<<<gS4, blk, 0, stream>>>(Y2, XFG, out_W, out_b, (float*)d_out, S);
}

// Round 4
// 1417.193 us; speedup vs baseline: 1.3045x; 1.1764x over previous
//
#include <hip/hip_runtime.h>
#include <math.h>

#define DEV __device__ __forceinline__

DEV float gelu_f(float x) { return 0.5f * x * (1.f + erff(x * 0.70710678118654752f)); }
DEV int rfl(int v) { return __builtin_amdgcn_readfirstlane(v); }

// ---------------- zero fill ----------------
__global__ void fill_zero(float* __restrict__ p, long n) {
  long i = (long)blockIdx.x * blockDim.x + threadIdx.x;
  long st = (long)gridDim.x * blockDim.x;
  for (; i < n; i += st) p[i] = 0.f;
}

// ---------------- CSR build: histogram ----------------
__global__ void hist_k(const int* __restrict__ key, int n, int* __restrict__ cnt) {
  int i = blockIdx.x * blockDim.x + threadIdx.x;
  int st = gridDim.x * blockDim.x;
  for (; i < n; i += st) atomicAdd(&cnt[key[i]], 1);
}

// ---------------- multi-block exclusive scan (3 passes, 1024 elems/block) ----------------
__global__ __launch_bounds__(256) void scan_p1(const int* __restrict__ cnt, int n,
                                               int* __restrict__ bsum) {
  __shared__ int ts[256];
  int base = blockIdx.x * 1024;
  int s = 0;
  #pragma unroll
  for (int k = 0; k < 4; ++k) {
    int g = base + threadIdx.x * 4 + k;
    if (g < n) s += cnt[g];
  }
  ts[threadIdx.x] = s;
  __syncthreads();
  for (int d = 128; d; d >>= 1) {
    if (threadIdx.x < d) ts[threadIdx.x] += ts[threadIdx.x + d];
    __syncthreads();
  }
  if (threadIdx.x == 0) bsum[blockIdx.x] = ts[0];
}

__global__ __launch_bounds__(256) void scan_p2(int* __restrict__ bsum, int nb,
                                               int* __restrict__ rp, int n) {
  __shared__ int ts[256];
  int tid = threadIdx.x;
  int v = (tid < nb) ? bsum[tid] : 0;
  ts[tid] = v;
  __syncthreads();
  for (int d = 1; d < 256; d <<= 1) {
    int w = (tid >= d) ? ts[tid - d] : 0;
    __syncthreads();
    ts[tid] += w;
    __syncthreads();
  }
  if (tid < nb) bsum[tid] = (tid == 0) ? 0 : ts[tid - 1];
  if (tid == 255) rp[n] = ts[255];
}

__global__ __launch_bounds__(256) void scan_p3(const int* __restrict__ cnt, int n,
                                               const int* __restrict__ bsum,
                                               int* __restrict__ rp, int* __restrict__ cursor) {
  __shared__ int ts[256];
  int base = blockIdx.x * 1024;
  int tid = threadIdx.x;
  int c[4];
  int s = 0;
  #pragma unroll
  for (int k = 0; k < 4; ++k) {
    int g = base + tid * 4 + k;
    c[k] = (g < n) ? cnt[g] : 0;
    s += c[k];
  }
  ts[tid] = s;
  __syncthreads();
  for (int d = 1; d < 256; d <<= 1) {
    int w = (tid >= d) ? ts[tid - d] : 0;
    __syncthreads();
    ts[tid] += w;
    __syncthreads();
  }
  int run = bsum[blockIdx.x] + ((tid == 0) ? 0 : ts[tid - 1]);
  #pragma unroll
  for (int k = 0; k < 4; ++k) {
    int g = base + tid * 4 + k;
    if (g < n) {
      rp[g] = run;
      cursor[g] = run;
      run += c[k];
    }
  }
}

// ---------------- CSR build: scatter edge ids ----------------
__global__ void scat_k(const int* __restrict__ key, int n,
                       int* __restrict__ cursor, int* __restrict__ eids) {
  int i = blockIdx.x * blockDim.x + threadIdx.x;
  int st = gridDim.x * blockDim.x;
  for (; i < n; i += st) {
    int p = atomicAdd(&cursor[key[i]], 1);
    eids[p] = i;
  }
}

// ---------------- compose We' = attr1_W @ We[l], be' = attr1_b @ We[l] ----------------
__global__ __launch_bounds__(256) void compose_we(
    const float* __restrict__ a1W, const float* __restrict__ a1b,
    const float* __restrict__ c1We, const float* __restrict__ c2We,
    float* __restrict__ WEC, float* __restrict__ BEC)
{
  int l = blockIdx.x;
  const float* We = (l < 3) ? (c1We + l * 4096) : (c2We + (l - 3) * 4096);
  __shared__ float wes[4096];
  int tid = threadIdx.x;
  for (int i = tid; i < 4096; i += 256) wes[i] = We[i];
  __syncthreads();
  for (int i = tid; i < 1024; i += 256) {
    int k = i >> 6, j = i & 63;
    float s = 0.f;
    #pragma unroll 16
    for (int m = 0; m < 64; ++m) s += a1W[k * 64 + m] * wes[m * 64 + j];
    WEC[l * 1024 + i] = s;
  }
  if (tid < 64) {
    float s = 0.f;
    for (int m = 0; m < 64; ++m) s += a1b[m] * wes[m * 64 + tid];
    BEC[l * 64 + tid] = s;
  }
}

// ---------------- tiled GEMM: O = act(X@W + b), 64 output cols, optional second W ----------------
template <int ACT, bool PAIR>
__global__ __launch_bounds__(256) void gemm_tile(
    const float* __restrict__ X, int nrows, int K,
    const float* __restrict__ W1, const float* __restrict__ b1, float* __restrict__ O1,
    const float* __restrict__ W2, const float* __restrict__ b2, float* __restrict__ O2)
{
  __shared__ float xs[64][68];
  __shared__ float ws1[64][68];
  __shared__ float ws2[PAIR ? 64 : 1][68];
  const int tid = threadIdx.x;
  const int row0 = blockIdx.x * 64;
  const int tr = tid >> 4;
  const int tc = tid & 15;
  float acc1[4][4] = {{0.f,0.f,0.f,0.f},{0.f,0.f,0.f,0.f},{0.f,0.f,0.f,0.f},{0.f,0.f,0.f,0.f}};
  float acc2[4][4] = {{0.f,0.f,0.f,0.f},{0.f,0.f,0.f,0.f},{0.f,0.f,0.f,0.f},{0.f,0.f,0.f,0.f}};

  for (int kc = 0; kc < K; kc += 64) {
    const int klen = min(64, K - kc);
    __syncthreads();
    for (int i = tid; i < 4096; i += 256) {
      int r = i >> 6, c = i & 63;
      int gr = row0 + r;
      float v = 0.f;
      if (gr < nrows && c < klen) v = X[(size_t)gr * K + kc + c];
      xs[r][c] = v;
      float w1v = 0.f, w2v = 0.f;
      if (r < klen) {
        w1v = W1[(size_t)(kc + r) * 64 + c];
        if (PAIR) w2v = W2[(size_t)(kc + r) * 64 + c];
      }
      ws1[r][c] = w1v;
      if (PAIR) ws2[r][c] = w2v;
    }
    __syncthreads();
    #pragma unroll 8
    for (int k = 0; k < 64; ++k) {
      float xv[4];
      #pragma unroll
      for (int i = 0; i < 4; ++i) xv[i] = xs[tr * 4 + i][k];
      float4 w1 = *(const float4*)&ws1[k][tc * 4];
      #pragma unroll
      for (int i = 0; i < 4; ++i) {
        acc1[i][0] += xv[i] * w1.x; acc1[i][1] += xv[i] * w1.y;
        acc1[i][2] += xv[i] * w1.z; acc1[i][3] += xv[i] * w1.w;
      }
      if (PAIR) {
        float4 w2 = *(const float4*)&ws2[k][tc * 4];
        #pragma unroll
        for (int i = 0; i < 4; ++i) {
          acc2[i][0] += xv[i] * w2.x; acc2[i][1] += xv[i] * w2.y;
          acc2[i][2] += xv[i] * w2.z; acc2[i][3] += xv[i] * w2.w;
        }
      }
    }
  }

  float4 bv1 = *(const float4*)&b1[tc * 4];
  float4 bv2 = bv1;
  if (PAIR) bv2 = *(const float4*)&b2[tc * 4];
  #pragma unroll
  for (int i = 0; i < 4; ++i) {
    int gr = row0 + tr * 4 + i;
    if (gr >= nrows) continue;
    float4 o;
    o.x = acc1[i][0] + bv1.x; o.y = acc1[i][1] + bv1.y;
    o.z = acc1[i][2] + bv1.z; o.w = acc1[i][3] + bv1.w;
    if (ACT == 1) { o.x = gelu_f(o.x); o.y = gelu_f(o.y); o.z = gelu_f(o.z); o.w = gelu_f(o.w); }
    *(float4*)&O1[(size_t)gr * 64 + tc * 4] = o;
    if (PAIR) {
      float4 p;
      p.x = acc2[i][0] + bv2.x; p.y = acc2[i][1] + bv2.y;
      p.z = acc2[i][2] + bv2.z; p.w = acc2[i][3] + bv2.w;
      *(float4*)&O2[(size_t)gr * 64 + tc * 4] = p;
    }
  }
}

// ---------------- fused dual-conv gather GATv2 layer (conv1-l + conv2-l share graph walk) ----
// wave per dst; WEC columns cached in registers; wave-uniform edge indices forced
// scalar via readfirstlane so attr rows become s_load + SGPR-operand v_fma.
__global__ __launch_bounds__(256) void gat_gather2(
    const int* __restrict__ rowptr, const int* __restrict__ eids,
    const int* __restrict__ esrc, const float* __restrict__ attr,
    const float* __restrict__ wec1, const float* __restrict__ bec1,
    const float* __restrict__ att1, const float* __restrict__ bias1,
    const float* __restrict__ wec2, const float* __restrict__ bec2,
    const float* __restrict__ att2, const float* __restrict__ bias2,
    const float* __restrict__ xl1, const float* __restrict__ xr1,
    const float* __restrict__ pre1, float* __restrict__ out1,
    const float* __restrict__ xl2, const float* __restrict__ xr2,
    const float* __restrict__ pre2, float* __restrict__ out2, int n)
{
  int tid = threadIdx.x;
  int wid = tid >> 6, lane = tid & 63;
  int d = blockIdx.x * 4 + wid;
  if (d >= n) return;
  float w1[16], w2[16];
  #pragma unroll
  for (int k = 0; k < 16; ++k) {
    w1[k] = wec1[k * 64 + lane];
    w2[k] = wec2[k * 64 + lane];
  }
  float be1 = bec1[lane], be2 = bec2[lane];
  float at1 = att1[lane], at2 = att2[lane];
  float xr1v = xr1[(size_t)d * 64 + lane];
  float xr2v = xr2[(size_t)d * 64 + lane];
  float n1 = 0.f, d1 = 0.f, n2 = 0.f, d2 = 0.f;
  int j0 = rowptr[d], j1 = rowptr[d + 1];
  for (int j = j0; j < j1; ++j) {
    int e = rfl(eids[j]);
    int s = rfl(esrc[e]);
    const float* arow = attr + (size_t)e * 16;
    float xl1v = xl1[(size_t)s * 64 + lane];
    float xl2v = xl2[(size_t)s * 64 + lane];
    float ep1 = be1, ep2 = be2;
    #pragma unroll
    for (int k = 0; k < 16; ++k) {
      float ak = arow[k];
      ep1 += ak * w1[k];
      ep2 += ak * w2[k];
    }
    float m1 = xl1v + xr1v + ep1;
    float m2 = xl2v + xr2v + ep2;
    float lr1 = m1 < 0.f ? 0.2f * m1 : m1;
    float lr2 = m2 < 0.f ? 0.2f * m2 : m2;
    float t1 = at1 * lr1, t2 = at2 * lr2;
    #pragma unroll
    for (int o = 32; o; o >>= 1) {
      t1 += __shfl_xor(t1, o, 64);
      t2 += __shfl_xor(t2, o, 64);
    }
    float ex1 = __expf(t1), ex2 = __expf(t2);
    n1 += ex1 * xl1v; d1 += ex1;
    n2 += ex2 * xl2v; d2 += ex2;
  }
  size_t base = (size_t)d * 64 + lane;
  float v1 = n1 / (d1 + 1e-16f) + bias1[lane];
  float v2 = n2 / (d2 + 1e-16f) + bias2[lane];
  out1[base] = gelu_f(v1) + pre1[base];
  out2[base] = gelu_f(v2) + pre2[base];
}

// ---------------- fused gather GATv2 (segment graph, edge_dim=1) ----------------
__global__ __launch_bounds__(256) void gat_seg_g(
    const int* __restrict__ rowptr, const int* __restrict__ eids,
    const int* __restrict__ ssrc, const float* __restrict__ vals,
    const float* __restrict__ we3, const float* __restrict__ att,
    const float* __restrict__ bias,
    const float* __restrict__ xl, const float* __restrict__ xr,
    float* __restrict__ out, int n)
{
  int tid = threadIdx.x;
  int wid = tid >> 6, lane = tid & 63;
  int d = blockIdx.x * 4 + wid;
  if (d >= n) return;
  float we3v = we3[lane], attv = att[lane], bsv = bias[lane];
  float xrv = xr[(size_t)d * 64 + lane];
  float accn = 0.f, accd = 0.f;
  int j1 = rowptr[d + 1];
  for (int j = rowptr[d]; j < j1; ++j) {
    int e = rfl(eids[j]);
    int s = rfl(ssrc[e]);
    float ep = vals[e] * we3v;
    float xlv = xl[(size_t)s * 64 + lane];
    float m = xlv + xrv + ep;
    float lr = m < 0.f ? 0.2f * m : m;
    float t = attv * lr;
    #pragma unroll
    for (int o = 32; o; o >>= 1) t += __shfl_xor(t, o, 64);
    float ex = __expf(t);
    accn += ex * xlv;
    accd += ex;
  }
  float v = accn / (accd + 1e-16f) + bsv;
  out[(size_t)d * 64 + lane] = gelu_f(v);
}

// ---------------- xf partial init ----------------
__global__ void xf_init(
    float* __restrict__ xf, const float* __restrict__ seg_embed,
    const float* __restrict__ time_embed, const float* __restrict__ week_embed,
    const int* __restrict__ cur_t, const int* __restrict__ cur_w, int S)
{
  long idx = (long)blockIdx.x * blockDim.x + threadIdx.x;
  if (idx >= (long)S * 192) return;
  int s = idx / 192, c = idx % 192;
  if (c < 64)       xf[(size_t)s * 448 + c]       = seg_embed[(size_t)s * 64 + c];
  else if (c < 128) xf[(size_t)s * 448 + 256 + c] = time_embed[cur_t[0] * 64 + (c - 64)];
  else              xf[(size_t)s * 448 + 256 + c] = week_embed[cur_w[0] * 64 + (c - 128)];
}

// ---------------- gather spmm se ----------------
__global__ __launch_bounds__(256) void spmm_se_g(
    const int* __restrict__ rowptr, const int* __restrict__ eids,
    const int* __restrict__ secol, const float* __restrict__ seval,
    const float* __restrict__ edge_embed, const float* __restrict__ attr,
    const float* __restrict__ W2, const float* __restrict__ b2,
    float* __restrict__ xf, int S)
{
  __shared__ float ws[1024];
  __shared__ float bs[64];
  int tid = threadIdx.x;
  for (int i = tid; i < 1024; i += 256) ws[i] = W2[i];
  if (tid < 64) bs[tid] = b2[tid];
  __syncthreads();
  int wid = tid >> 6, lane = tid & 63;
  int s = blockIdx.x * 4 + wid;
  if (s >= S) return;
  float acc1 = 0.f, aat = 0.f, vs = 0.f;
  int j1 = rowptr[s + 1];
  for (int j = rowptr[s]; j < j1; ++j) {
    int e = rfl(eids[j]);
    int c = rfl(secol[e]);
    float v = seval[e];
    acc1 += v * edge_embed[(size_t)c * 64 + lane];
    aat  += v * attr[(size_t)c * 16 + (lane & 15)];
    vs   += v;
  }
  float x2 = vs * bs[lane];
  #pragma unroll
  for (int k = 0; k < 16; ++k)
    x2 += __shfl(aat, k, 64) * ws[k * 64 + lane];
  xf[(size_t)s * 448 + 64 + lane]  = acc1;
  xf[(size_t)s * 448 + 128 + lane] = x2;
}

// ---------------- gather spmm sn ----------------
__global__ __launch_bounds__(256) void spmm_sn_g(
    const int* __restrict__ rowptr, const int* __restrict__ eids,
    const int* __restrict__ sncol, const float* __restrict__ snval,
    const float* __restrict__ h, const float* __restrict__ nf,
    float* __restrict__ xf, int S)
{
  int tid = threadIdx.x;
  int wid = tid >> 6, lane = tid & 63;
  int s = blockIdx.x * 4 + wid;
  if (s >= S) return;
  float acch = 0.f, accf = 0.f;
  int j1 = rowptr[s + 1];
  for (int j = rowptr[s]; j < j1; ++j) {
    int e = rfl(eids[j]);
    int c = rfl(sncol[e]);
    float v = snval[e];
    acch += v * h[(size_t)c * 64 + lane];
    accf += v * nf[(size_t)c * 64 + lane];
  }
  xf[(size_t)s * 448 + 192 + lane] = acch;
  xf[(size_t)s * 448 + 256 + lane] = accf;
}

// ---------------- head ----------------
__global__ __launch_bounds__(256) void head_k(
    const float* __restrict__ y2, const float* __restrict__ xfg,
    const float* __restrict__ outW, const float* __restrict__ outb,
    float* __restrict__ out, int S)
{
  int wid = threadIdx.x >> 6, lane = threadIdx.x & 63;
  int s = blockIdx.x * 4 + wid;
  if (s >= S) return;
  float t = y2[(size_t)s * 64 + lane] * outW[lane] + xfg[(size_t)s * 64 + lane] * outW[64 + lane];
  #pragma unroll
  for (int o = 32; o; o >>= 1) t += __shfl_xor(t, o, 64);
  if (lane == 0) {
    float z = t + outb[0];
    out[s] = 3600.f / (1.f + __expf(-z));
  }
}

extern "C" void kernel_launch(void* const* d_in, const int* in_sizes, int n_in,
                              void* d_out, int out_size, void* d_ws, size_t ws_size,
                              hipStream_t stream)
{
  const float* x_rec       = (const float*)d_in[0];
  const float* attr        = (const float*)d_in[1];
  const float* se_val      = (const float*)d_in[2];
  const float* sn_val      = (const float*)d_in[3];
  const float* ss_val      = (const float*)d_in[4];
  const float* node_embed  = (const float*)d_in[5];
  const float* edge_embed  = (const float*)d_in[6];
  const float* seg_embed   = (const float*)d_in[7];
  const float* time_embed  = (const float*)d_in[8];
  const float* week_embed  = (const float*)d_in[9];
  const float* node_lin_W  = (const float*)d_in[10];
  const float* node_lin_b  = (const float*)d_in[11];
  const float* attr2_W     = (const float*)d_in[14];
  const float* attr2_b     = (const float*)d_in[15];
  const float* c1_Wl       = (const float*)d_in[16];
  const float* c1_bl       = (const float*)d_in[17];
  const float* c1_Wr       = (const float*)d_in[18];
  const float* c1_br       = (const float*)d_in[19];
  const float* c1_att      = (const float*)d_in[21];
  const float* c1_bias     = (const float*)d_in[22];
  const float* c2_Wl       = (const float*)d_in[23];
  const float* c2_bl       = (const float*)d_in[24];
  const float* c2_Wr       = (const float*)d_in[25];
  const float* c2_br       = (const float*)d_in[26];
  const float* c2_att      = (const float*)d_in[28];
  const float* c2_bias     = (const float*)d_in[29];
  const float* c3_Wl       = (const float*)d_in[30];
  const float* c3_bl       = (const float*)d_in[31];
  const float* c3_Wr       = (const float*)d_in[32];
  const float* c3_br       = (const float*)d_in[33];
  const float* c3_We       = (const float*)d_in[34];
  const float* c3_att      = (const float*)d_in[35];
  const float* c3_bias     = (const float*)d_in[36];
  const float* lin1_W      = (const float*)d_in[37];
  const float* lin1_b      = (const float*)d_in[38];
  const float* lin2_W      = (const float*)d_in[39];
  const float* lin2_b      = (const float*)d_in[40];
  const float* out_W       = (const float*)d_in[41];
  const float* out_b       = (const float*)d_in[42];
  const int* edge_index    = (const int*)d_in[43];
  const int* se_row        = (const int*)d_in[44];
  const int* se_col        = (const int*)d_in[45];
  const int* sn_row        = (const int*)d_in[46];
  const int* sn_col        = (const int*)d_in[47];
  const int* ss_row        = (const int*)d_in[48];
  const int* ss_col        = (const int*)d_in[49];
  const int* cur_t         = (const int*)d_in[50];
  const int* cur_w         = (const int*)d_in[51];

  const int N = in_sizes[0] / 32;
  const int E = in_sizes[1] / 16;
  const int S = in_sizes[7] / 64;
  const int NNZSS = in_sizes[4];

  // workspace layout
  float* W = (float*)d_ws;
  size_t o = 0;
  float* A   = W + o; o += (size_t)N * 64;   // conv1 xl / xl3
  float* B   = W + o; o += (size_t)N * 64;   // conv1 xr / xr3
  float* A2  = W + o; o += (size_t)N * 64;   // conv2 xl
  float* B2  = W + o; o += (size_t)N * 64;   // conv2 xr
  float* Hc  = W + o; o += (size_t)N * 64;   // conv1 state / final h
  float* F0  = W + o; o += (size_t)N * 64;   // nf0 (conv2 pre)
  float* Fc  = W + o; o += (size_t)N * 64;   // conv2 state / final nf
  float* XF  = W + o; o += (size_t)S * 448;  // xf [S,448]
  float* XFG = W + o; o += (size_t)S * 64;
  float* Y   = W + o; o += (size_t)S * 64;
  float* Y2  = W + o; o += (size_t)S * 64;
  float* WEC = W + o; o += 6 * 1024;
  float* BEC = W + o; o += 6 * 64;
  // CSR arrays (ints)
  int* I = (int*)(W + o);
  size_t q = 0;
  int* cur1 = I + q; q += N + 1;
  int* cur2 = I + q; q += S + 1;
  int* cur3 = I + q; q += S + 1;
  int* cur4 = I + q; q += S + 1;
  int* rp1  = I + q; q += N + 1;
  int* rp2  = I + q; q += S + 1;
  int* rp3  = I + q; q += S + 1;
  int* rp4  = I + q; q += S + 1;
  int* eid1 = I + q; q += E;
  int* eid2 = I + q; q += E;
  int* eid3 = I + q; q += E;
  int* eid4 = I + q; q += NNZSS;
  int* bs1  = I + q; q += 256;
  int* bs2  = I + q; q += 256;
  int* bs3  = I + q; q += 256;
  int* bs4  = I + q; q += 256;

  const int* edst = edge_index + E;

  dim3 blk(256);
  const int gN64 = (N + 63) / 64;
  const int gS64 = (S + 63) / 64;
  const int gN4  = (N + 3) / 4;
  const int gS4  = (S + 3) / 4;
  const int nbN  = (N + 1 + 1023) / 1024;
  const int nbS  = (S + 1 + 1023) / 1024;

  // ---- CSR builds ----
  long ztot = (long)(N + 1) + 3L * (S + 1);
  fill_zero<<<256, blk, 0, stream>>>((float*)cur1, ztot);
  hist_k<<<512, blk, 0, stream>>>(edst,   E,     cur1);
  hist_k<<<512, blk, 0, stream>>>(se_row, E,     cur2);
  hist_k<<<512, blk, 0, stream>>>(sn_row, E,     cur3);
  hist_k<<<512, blk, 0, stream>>>(ss_col, NNZSS, cur4);

  scan_p1<<<nbN, blk, 0, stream>>>(cur1, N + 1, bs1);
  scan_p1<<<nbS, blk, 0, stream>>>(cur2, S + 1, bs2);
  scan_p1<<<nbS, blk, 0, stream>>>(cur3, S + 1, bs3);
  scan_p1<<<nbS, blk, 0, stream>>>(cur4, S + 1, bs4);
  scan_p2<<<1, blk, 0, stream>>>(bs1, nbN, rp1, N);
  scan_p2<<<1, blk, 0, stream>>>(bs2, nbS, rp2, S);
  scan_p2<<<1, blk, 0, stream>>>(bs3, nbS, rp3, S);
  scan_p2<<<1, blk, 0, stream>>>(bs4, nbS, rp4, S);
  scan_p3<<<nbN, blk, 0, stream>>>(cur1, N, bs1, rp1, cur1);
  scan_p3<<<nbS, blk, 0, stream>>>(cur2, S, bs2, rp2, cur2);
  scan_p3<<<nbS, blk, 0, stream>>>(cur3, S, bs3, rp3, cur3);
  scan_p3<<<nbS, blk, 0, stream>>>(cur4, S, bs4, rp4, cur4);

  scat_k<<<512, blk, 0, stream>>>(edst,   E,     cur1, eid1);
  scat_k<<<512, blk, 0, stream>>>(se_row, E,     cur2, eid2);
  scat_k<<<512, blk, 0, stream>>>(sn_row, E,     cur3, eid3);
  scat_k<<<512, blk, 0, stream>>>(ss_col, NNZSS, cur4, eid4);

  // composed edge-projection weights
  compose_we<<<6, blk, 0, stream>>>((const float*)d_in[12], (const float*)d_in[13],
                                    (const float*)d_in[20], (const float*)d_in[27], WEC, BEC);

  // nf0 = gelu(x_rec @ node_lin_W + b)   (K=32)
  gemm_tile<1, false><<<gN64, blk, 0, stream>>>(x_rec, N, 32, node_lin_W, node_lin_b, F0,
                                                nullptr, nullptr, nullptr);

  // fused conv1+conv2 stacks (pre1 = node_embed, pre2 = F0)
  const float* st1 = node_embed;
  const float* st2 = F0;
  for (int l = 0; l < 3; ++l) {
    gemm_tile<0, true><<<gN64, blk, 0, stream>>>(st1, N, 64,
        c1_Wl + l * 4096, c1_bl + l * 64, A, c1_Wr + l * 4096, c1_br + l * 64, B);
    gemm_tile<0, true><<<gN64, blk, 0, stream>>>(st2, N, 64,
        c2_Wl + l * 4096, c2_bl + l * 64, A2, c2_Wr + l * 4096, c2_br + l * 64, B2);
    gat_gather2<<<gN4, blk, 0, stream>>>(rp1, eid1, edge_index, attr,
        WEC + l * 1024, BEC + l * 64, c1_att + l * 64, c1_bias + l * 64,
        WEC + (3 + l) * 1024, BEC + (3 + l) * 64, c2_att + l * 64, c2_bias + l * 64,
        A, B, node_embed, Hc,
        A2, B2, F0, Fc, N);
    st1 = Hc;
    st2 = Fc;
  }

  // xf assembly
  xf_init<<<((long)S * 192 + 255) / 256, blk, 0, stream>>>(XF, seg_embed, time_embed, week_embed,
                                                           cur_t, cur_w, S);
  spmm_se_g<<<gS4, blk, 0, stream>>>(rp2, eid2, se_col, se_val, edge_embed, attr,
                                     attr2_W, attr2_b, XF, S);
  spmm_sn_g<<<gS4, blk, 0, stream>>>(rp3, eid3, sn_col, sn_val, Hc, Fc, XF, S);

  // conv3 on segment graph (K=448)
  gemm_tile<0, true><<<gS64, blk, 0, stream>>>(XF, S, 448, c3_Wl, c3_bl, A, c3_Wr, c3_br, B);
  gat_seg_g<<<gS4, blk, 0, stream>>>(rp4, eid4, ss_row, ss_val, c3_We, c3_att, c3_bias,
                                     A, B, XFG, S);

  // MLP head
  gemm_tile<1, false><<<gS64, blk, 0, stream>>>(XF, S, 448, lin1_W, lin1_b, Y,
                                                nullptr, nullptr, nullptr);
  gemm_tile<1, false><<<gS64, blk, 0, stream>>>(Y, S, 64, lin2_W, lin2_b, Y2,
                                                nullptr, nullptr, nullptr);
  head_k<<<gS4, blk, 0, stream>>>(Y2, XFG, out_W, out_b, (float*)d_out, S);
}

// Round 5
// 1128.117 us; speedup vs baseline: 1.6388x; 1.2562x over previous
//
#include <hip/hip_runtime.h>
#include <hip/hip_bf16.h>
#include <math.h>

#define DEV __device__ __forceinline__
typedef unsigned short u16;

DEV float gelu_f(float x) { return 0.5f * x * (1.f + erff(x * 0.70710678118654752f)); }
DEV int rfl(int v) { return __builtin_amdgcn_readfirstlane(v); }
DEV float rflf(float v) {
  int i = __builtin_amdgcn_readfirstlane(__float_as_int(v));
  return __int_as_float(i);
}
DEV u16 f2b(float x) { __hip_bfloat16 h = __float2bfloat16(x); return *reinterpret_cast<u16*>(&h); }
DEV float b2f(u16 u) { __hip_bfloat16 h; *reinterpret_cast<u16*>(&h) = u; return __bfloat162float(h); }

// ---------------- zero fill ----------------
__global__ void fill_zero(float* __restrict__ p, long n) {
  long i = (long)blockIdx.x * blockDim.x + threadIdx.x;
  long st = (long)gridDim.x * blockDim.x;
  for (; i < n; i += st) p[i] = 0.f;
}

// ---------------- CSR build: histogram ----------------
__global__ void hist_k(const int* __restrict__ key, int n, int* __restrict__ cnt) {
  int i = blockIdx.x * blockDim.x + threadIdx.x;
  int st = gridDim.x * blockDim.x;
  for (; i < n; i += st) atomicAdd(&cnt[key[i]], 1);
}

// ---------------- multi-block exclusive scan (3 passes, 1024 elems/block) ----------------
__global__ __launch_bounds__(256) void scan_p1(const int* __restrict__ cnt, int n,
                                               int* __restrict__ bsum) {
  __shared__ int ts[256];
  int base = blockIdx.x * 1024;
  int s = 0;
  #pragma unroll
  for (int k = 0; k < 4; ++k) {
    int g = base + threadIdx.x * 4 + k;
    if (g < n) s += cnt[g];
  }
  ts[threadIdx.x] = s;
  __syncthreads();
  for (int d = 128; d; d >>= 1) {
    if (threadIdx.x < d) ts[threadIdx.x] += ts[threadIdx.x + d];
    __syncthreads();
  }
  if (threadIdx.x == 0) bsum[blockIdx.x] = ts[0];
}

__global__ __launch_bounds__(256) void scan_p2(int* __restrict__ bsum, int nb,
                                               int* __restrict__ rp, int n) {
  __shared__ int ts[256];
  int tid = threadIdx.x;
  int v = (tid < nb) ? bsum[tid] : 0;
  ts[tid] = v;
  __syncthreads();
  for (int d = 1; d < 256; d <<= 1) {
    int w = (tid >= d) ? ts[tid - d] : 0;
    __syncthreads();
    ts[tid] += w;
    __syncthreads();
  }
  if (tid < nb) bsum[tid] = (tid == 0) ? 0 : ts[tid - 1];
  if (tid == 255) rp[n] = ts[255];
}

__global__ __launch_bounds__(256) void scan_p3(const int* __restrict__ cnt, int n,
                                               const int* __restrict__ bsum,
                                               int* __restrict__ rp, int* __restrict__ cursor) {
  __shared__ int ts[256];
  int base = blockIdx.x * 1024;
  int tid = threadIdx.x;
  int c[4];
  int s = 0;
  #pragma unroll
  for (int k = 0; k < 4; ++k) {
    int g = base + tid * 4 + k;
    c[k] = (g < n) ? cnt[g] : 0;
    s += c[k];
  }
  ts[tid] = s;
  __syncthreads();
  for (int d = 1; d < 256; d <<= 1) {
    int w = (tid >= d) ? ts[tid - d] : 0;
    __syncthreads();
    ts[tid] += w;
    __syncthreads();
  }
  int run = bsum[blockIdx.x] + ((tid == 0) ? 0 : ts[tid - 1]);
  #pragma unroll
  for (int k = 0; k < 4; ++k) {
    int g = base + tid * 4 + k;
    if (g < n) {
      rp[g] = run;
      cursor[g] = run;
      run += c[k];
    }
  }
}

// ---------------- CSR build: scatter (stores payloads, killing the eids indirection) ----
__global__ void scat_pair_k(const int* __restrict__ key, const int* __restrict__ aux,
                            const float* __restrict__ val, int n,
                            int* __restrict__ cursor, int* __restrict__ auxs,
                            float* __restrict__ vals, int* __restrict__ eids) {
  int i = blockIdx.x * blockDim.x + threadIdx.x;
  int st = gridDim.x * blockDim.x;
  for (; i < n; i += st) {
    int p = atomicAdd(&cursor[key[i]], 1);
    auxs[p] = aux[i];
    if (vals) vals[p] = val[i];
    if (eids) eids[p] = i;
  }
}

// ---------------- compose We' = attr1_W @ We[l], be' = attr1_b @ We[l] ----------------
__global__ __launch_bounds__(256) void compose_we(
    const float* __restrict__ a1W, const float* __restrict__ a1b,
    const float* __restrict__ c1We, const float* __restrict__ c2We,
    float* __restrict__ WEC, float* __restrict__ BEC)
{
  int l = blockIdx.x;
  const float* We = (l < 3) ? (c1We + l * 4096) : (c2We + (l - 3) * 4096);
  __shared__ float wes[4096];
  int tid = threadIdx.x;
  for (int i = tid; i < 4096; i += 256) wes[i] = We[i];
  __syncthreads();
  for (int i = tid; i < 1024; i += 256) {
    int k = i >> 6, j = i & 63;
    float s = 0.f;
    #pragma unroll 16
    for (int m = 0; m < 64; ++m) s += a1W[k * 64 + m] * wes[m * 64 + j];
    WEC[l * 1024 + i] = s;
  }
  if (tid < 64) {
    float s = 0.f;
    for (int m = 0; m < 64; ++m) s += a1b[m] * wes[m * 64 + tid];
    BEC[l * 64 + tid] = s;
  }
}

// ---------------- tiled GEMM: O = act(X@W + b); OBF -> bf16 output ----------------
template <int ACT, bool PAIR, bool OBF>
__global__ __launch_bounds__(256) void gemm_tile(
    const float* __restrict__ X, int nrows, int K,
    const float* __restrict__ W1, const float* __restrict__ b1, void* __restrict__ O1v,
    const float* __restrict__ W2, const float* __restrict__ b2, void* __restrict__ O2v)
{
  __shared__ float xs[64][68];
  __shared__ float ws1[64][68];
  __shared__ float ws2[PAIR ? 64 : 1][68];
  const int tid = threadIdx.x;
  const int row0 = blockIdx.x * 64;
  const int tr = tid >> 4;
  const int tc = tid & 15;
  float acc1[4][4] = {{0.f,0.f,0.f,0.f},{0.f,0.f,0.f,0.f},{0.f,0.f,0.f,0.f},{0.f,0.f,0.f,0.f}};
  float acc2[4][4] = {{0.f,0.f,0.f,0.f},{0.f,0.f,0.f,0.f},{0.f,0.f,0.f,0.f},{0.f,0.f,0.f,0.f}};

  for (int kc = 0; kc < K; kc += 64) {
    const int klen = min(64, K - kc);
    __syncthreads();
    for (int i = tid; i < 4096; i += 256) {
      int r = i >> 6, c = i & 63;
      int gr = row0 + r;
      float v = 0.f;
      if (gr < nrows && c < klen) v = X[(size_t)gr * K + kc + c];
      xs[r][c] = v;
      float w1v = 0.f, w2v = 0.f;
      if (r < klen) {
        w1v = W1[(size_t)(kc + r) * 64 + c];
        if (PAIR) w2v = W2[(size_t)(kc + r) * 64 + c];
      }
      ws1[r][c] = w1v;
      if (PAIR) ws2[r][c] = w2v;
    }
    __syncthreads();
    #pragma unroll 8
    for (int k = 0; k < 64; ++k) {
      float xv[4];
      #pragma unroll
      for (int i = 0; i < 4; ++i) xv[i] = xs[tr * 4 + i][k];
      float4 w1 = *(const float4*)&ws1[k][tc * 4];
      #pragma unroll
      for (int i = 0; i < 4; ++i) {
        acc1[i][0] += xv[i] * w1.x; acc1[i][1] += xv[i] * w1.y;
        acc1[i][2] += xv[i] * w1.z; acc1[i][3] += xv[i] * w1.w;
      }
      if (PAIR) {
        float4 w2 = *(const float4*)&ws2[k][tc * 4];
        #pragma unroll
        for (int i = 0; i < 4; ++i) {
          acc2[i][0] += xv[i] * w2.x; acc2[i][1] += xv[i] * w2.y;
          acc2[i][2] += xv[i] * w2.z; acc2[i][3] += xv[i] * w2.w;
        }
      }
    }
  }

  float4 bv1 = *(const float4*)&b1[tc * 4];
  float4 bv2 = bv1;
  if (PAIR) bv2 = *(const float4*)&b2[tc * 4];
  #pragma unroll
  for (int i = 0; i < 4; ++i) {
    int gr = row0 + tr * 4 + i;
    if (gr >= nrows) continue;
    float4 o;
    o.x = acc1[i][0] + bv1.x; o.y = acc1[i][1] + bv1.y;
    o.z = acc1[i][2] + bv1.z; o.w = acc1[i][3] + bv1.w;
    if (ACT == 1) { o.x = gelu_f(o.x); o.y = gelu_f(o.y); o.z = gelu_f(o.z); o.w = gelu_f(o.w); }
    if (OBF) {
      ushort4 st;
      st.x = f2b(o.x); st.y = f2b(o.y); st.z = f2b(o.z); st.w = f2b(o.w);
      *(ushort4*)&((u16*)O1v)[(size_t)gr * 64 + tc * 4] = st;
    } else {
      *(float4*)&((float*)O1v)[(size_t)gr * 64 + tc * 4] = o;
    }
    if (PAIR) {
      float4 p;
      p.x = acc2[i][0] + bv2.x; p.y = acc2[i][1] + bv2.y;
      p.z = acc2[i][2] + bv2.z; p.w = acc2[i][3] + bv2.w;
      if (OBF) {
        ushort4 st;
        st.x = f2b(p.x); st.y = f2b(p.y); st.z = f2b(p.z); st.w = f2b(p.w);
        *(ushort4*)&((u16*)O2v)[(size_t)gr * 64 + tc * 4] = st;
      } else {
        *(float4*)&((float*)O2v)[(size_t)gr * 64 + tc * 4] = p;
      }
    }
  }
}

// ---------------- fused dual-conv gather GATv2 layer (bf16 xl/xr) ----------------
__global__ __launch_bounds__(256) void gat_gather2(
    const int* __restrict__ rowptr, const int* __restrict__ eids,
    const int* __restrict__ srcs, const float* __restrict__ attr,
    const float* __restrict__ wec1, const float* __restrict__ bec1,
    const float* __restrict__ att1, const float* __restrict__ bias1,
    const float* __restrict__ wec2, const float* __restrict__ bec2,
    const float* __restrict__ att2, const float* __restrict__ bias2,
    const u16* __restrict__ xl1, const u16* __restrict__ xr1,
    const float* __restrict__ pre1, float* __restrict__ out1,
    const u16* __restrict__ xl2, const u16* __restrict__ xr2,
    const float* __restrict__ pre2, float* __restrict__ out2, int n)
{
  int tid = threadIdx.x;
  int wid = tid >> 6, lane = tid & 63;
  int d = blockIdx.x * 4 + wid;
  if (d >= n) return;
  float w1[16], w2[16];
  #pragma unroll
  for (int k = 0; k < 16; ++k) {
    w1[k] = wec1[k * 64 + lane];
    w2[k] = wec2[k * 64 + lane];
  }
  float be1 = bec1[lane], be2 = bec2[lane];
  float at1 = att1[lane], at2 = att2[lane];
  float xr1v = b2f(xr1[(size_t)d * 64 + lane]);
  float xr2v = b2f(xr2[(size_t)d * 64 + lane]);
  float n1 = 0.f, d1 = 0.f, n2 = 0.f, d2 = 0.f;
  int j0 = rfl(rowptr[d]), j1 = rfl(rowptr[d + 1]);
  for (int j = j0; j < j1; ++j) {
    int e = rfl(eids[j]);
    int s = rfl(srcs[j]);
    const float* arow = attr + (size_t)e * 16;
    float xl1v = b2f(xl1[(size_t)s * 64 + lane]);
    float xl2v = b2f(xl2[(size_t)s * 64 + lane]);
    float ep1 = be1, ep2 = be2;
    #pragma unroll
    for (int k = 0; k < 16; ++k) {
      float ak = arow[k];
      ep1 += ak * w1[k];
      ep2 += ak * w2[k];
    }
    float m1 = xl1v + xr1v + ep1;
    float m2 = xl2v + xr2v + ep2;
    float lr1 = m1 < 0.f ? 0.2f * m1 : m1;
    float lr2 = m2 < 0.f ? 0.2f * m2 : m2;
    float t1 = at1 * lr1, t2 = at2 * lr2;
    #pragma unroll
    for (int o = 32; o; o >>= 1) {
      t1 += __shfl_xor(t1, o, 64);
      t2 += __shfl_xor(t2, o, 64);
    }
    float ex1 = __expf(t1), ex2 = __expf(t2);
    n1 += ex1 * xl1v; d1 += ex1;
    n2 += ex2 * xl2v; d2 += ex2;
  }
  size_t base = (size_t)d * 64 + lane;
  float v1 = n1 / (d1 + 1e-16f) + bias1[lane];
  float v2 = n2 / (d2 + 1e-16f) + bias2[lane];
  out1[base] = gelu_f(v1) + pre1[base];
  out2[base] = gelu_f(v2) + pre2[base];
}

// ---------------- fused gather GATv2 (segment graph, edge_dim=1, bf16 xl/xr) ----------------
__global__ __launch_bounds__(256) void gat_seg_g(
    const int* __restrict__ rowptr, const int* __restrict__ srcs,
    const float* __restrict__ vals,
    const float* __restrict__ we3, const float* __restrict__ att,
    const float* __restrict__ bias,
    const u16* __restrict__ xl, const u16* __restrict__ xr,
    float* __restrict__ out, int n)
{
  int tid = threadIdx.x;
  int wid = tid >> 6, lane = tid & 63;
  int d = blockIdx.x * 4 + wid;
  if (d >= n) return;
  float we3v = we3[lane], attv = att[lane], bsv = bias[lane];
  float xrv = b2f(xr[(size_t)d * 64 + lane]);
  float accn = 0.f, accd = 0.f;
  int j0 = rfl(rowptr[d]), j1 = rfl(rowptr[d + 1]);
  for (int j = j0; j < j1; ++j) {
    int s = rfl(srcs[j]);
    float vv = rflf(vals[j]);
    float ep = vv * we3v;
    float xlv = b2f(xl[(size_t)s * 64 + lane]);
    float m = xlv + xrv + ep;
    float lr = m < 0.f ? 0.2f * m : m;
    float t = attv * lr;
    #pragma unroll
    for (int o = 32; o; o >>= 1) t += __shfl_xor(t, o, 64);
    float ex = __expf(t);
    accn += ex * xlv;
    accd += ex;
  }
  float v = accn / (accd + 1e-16f) + bsv;
  out[(size_t)d * 64 + lane] = gelu_f(v);
}

// ---------------- xf partial init ----------------
__global__ void xf_init(
    float* __restrict__ xf, const float* __restrict__ seg_embed,
    const float* __restrict__ time_embed, const float* __restrict__ week_embed,
    const int* __restrict__ cur_t, const int* __restrict__ cur_w, int S)
{
  long idx = (long)blockIdx.x * blockDim.x + threadIdx.x;
  if (idx >= (long)S * 192) return;
  int s = idx / 192, c = idx % 192;
  if (c < 64)       xf[(size_t)s * 448 + c]       = seg_embed[(size_t)s * 64 + c];
  else if (c < 128) xf[(size_t)s * 448 + 256 + c] = time_embed[cur_t[0] * 64 + (c - 64)];
  else              xf[(size_t)s * 448 + 256 + c] = week_embed[cur_w[0] * 64 + (c - 128)];
}

// ---------------- gather spmm se ----------------
__global__ __launch_bounds__(256) void spmm_se_g(
    const int* __restrict__ rowptr, const int* __restrict__ cols,
    const float* __restrict__ vals,
    const float* __restrict__ edge_embed, const float* __restrict__ attr,
    const float* __restrict__ W2, const float* __restrict__ b2,
    float* __restrict__ xf, int S)
{
  __shared__ float ws[1024];
  __shared__ float bs[64];
  int tid = threadIdx.x;
  for (int i = tid; i < 1024; i += 256) ws[i] = W2[i];
  if (tid < 64) bs[tid] = b2[tid];
  __syncthreads();
  int wid = tid >> 6, lane = tid & 63;
  int s = blockIdx.x * 4 + wid;
  if (s >= S) return;
  float acc1 = 0.f, aat = 0.f, vs = 0.f;
  int j0 = rfl(rowptr[s]), j1 = rfl(rowptr[s + 1]);
  for (int j = j0; j < j1; ++j) {
    int c = rfl(cols[j]);
    float v = rflf(vals[j]);
    acc1 += v * edge_embed[(size_t)c * 64 + lane];
    aat  += v * attr[(size_t)c * 16 + (lane & 15)];
    vs   += v;
  }
  float x2 = vs * bs[lane];
  #pragma unroll
  for (int k = 0; k < 16; ++k)
    x2 += __shfl(aat, k, 64) * ws[k * 64 + lane];
  xf[(size_t)s * 448 + 64 + lane]  = acc1;
  xf[(size_t)s * 448 + 128 + lane] = x2;
}

// ---------------- gather spmm sn ----------------
__global__ __launch_bounds__(256) void spmm_sn_g(
    const int* __restrict__ rowptr, const int* __restrict__ cols,
    const float* __restrict__ vals,
    const float* __restrict__ h, const float* __restrict__ nf,
    float* __restrict__ xf, int S)
{
  int tid = threadIdx.x;
  int wid = tid >> 6, lane = tid & 63;
  int s = blockIdx.x * 4 + wid;
  if (s >= S) return;
  float acch = 0.f, accf = 0.f;
  int j0 = rfl(rowptr[s]), j1 = rfl(rowptr[s + 1]);
  for (int j = j0; j < j1; ++j) {
    int c = rfl(cols[j]);
    float v = rflf(vals[j]);
    acch += v * h[(size_t)c * 64 + lane];
    accf += v * nf[(size_t)c * 64 + lane];
  }
  xf[(size_t)s * 448 + 192 + lane] = acch;
  xf[(size_t)s * 448 + 256 + lane] = accf;
}

// ---------------- head ----------------
__global__ __launch_bounds__(256) void head_k(
    const float* __restrict__ y2, const float* __restrict__ xfg,
    const float* __restrict__ outW, const float* __restrict__ outb,
    float* __restrict__ out, int S)
{
  int wid = threadIdx.x >> 6, lane = threadIdx.x & 63;
  int s = blockIdx.x * 4 + wid;
  if (s >= S) return;
  float t = y2[(size_t)s * 64 + lane] * outW[lane] + xfg[(size_t)s * 64 + lane] * outW[64 + lane];
  #pragma unroll
  for (int o = 32; o; o >>= 1) t += __shfl_xor(t, o, 64);
  if (lane == 0) {
    float z = t + outb[0];
    out[s] = 3600.f / (1.f + __expf(-z));
  }
}

extern "C" void kernel_launch(void* const* d_in, const int* in_sizes, int n_in,
                              void* d_out, int out_size, void* d_ws, size_t ws_size,
                              hipStream_t stream)
{
  const float* x_rec       = (const float*)d_in[0];
  const float* attr        = (const float*)d_in[1];
  const float* se_val      = (const float*)d_in[2];
  const float* sn_val      = (const float*)d_in[3];
  const float* ss_val      = (const float*)d_in[4];
  const float* node_embed  = (const float*)d_in[5];
  const float* edge_embed  = (const float*)d_in[6];
  const float* seg_embed   = (const float*)d_in[7];
  const float* time_embed  = (const float*)d_in[8];
  const float* week_embed  = (const float*)d_in[9];
  const float* node_lin_W  = (const float*)d_in[10];
  const float* node_lin_b  = (const float*)d_in[11];
  const float* attr2_W     = (const float*)d_in[14];
  const float* attr2_b     = (const float*)d_in[15];
  const float* c1_Wl       = (const float*)d_in[16];
  const float* c1_bl       = (const float*)d_in[17];
  const float* c1_Wr       = (const float*)d_in[18];
  const float* c1_br       = (const float*)d_in[19];
  const float* c1_att      = (const float*)d_in[21];
  const float* c1_bias     = (const float*)d_in[22];
  const float* c2_Wl       = (const float*)d_in[23];
  const float* c2_bl       = (const float*)d_in[24];
  const float* c2_Wr       = (const float*)d_in[25];
  const float* c2_br       = (const float*)d_in[26];
  const float* c2_att      = (const float*)d_in[28];
  const float* c2_bias     = (const float*)d_in[29];
  const float* c3_Wl       = (const float*)d_in[30];
  const float* c3_bl       = (const float*)d_in[31];
  const float* c3_Wr       = (const float*)d_in[32];
  const float* c3_br       = (const float*)d_in[33];
  const float* c3_We       = (const float*)d_in[34];
  const float* c3_att      = (const float*)d_in[35];
  const float* c3_bias     = (const float*)d_in[36];
  const float* lin1_W      = (const float*)d_in[37];
  const float* lin1_b      = (const float*)d_in[38];
  const float* lin2_W      = (const float*)d_in[39];
  const float* lin2_b      = (const float*)d_in[40];
  const float* out_W       = (const float*)d_in[41];
  const float* out_b       = (const float*)d_in[42];
  const int* edge_index    = (const int*)d_in[43];
  const int* se_row        = (const int*)d_in[44];
  const int* se_col        = (const int*)d_in[45];
  const int* sn_row        = (const int*)d_in[46];
  const int* sn_col        = (const int*)d_in[47];
  const int* ss_row        = (const int*)d_in[48];
  const int* ss_col        = (const int*)d_in[49];
  const int* cur_t         = (const int*)d_in[50];
  const int* cur_w         = (const int*)d_in[51];

  const int N = in_sizes[0] / 32;
  const int E = in_sizes[1] / 16;
  const int S = in_sizes[7] / 64;
  const int NNZSS = in_sizes[4];

  // workspace layout (floats)
  float* W = (float*)d_ws;
  size_t o = 0;
  // bf16 pair-GEMM outputs (N*64 bf16 = N*32 floats each)
  u16* A  = (u16*)(W + o); o += (size_t)N * 32;  // conv1 xl / conv3 xl
  u16* B  = (u16*)(W + o); o += (size_t)N * 32;  // conv1 xr / conv3 xr
  u16* A2 = (u16*)(W + o); o += (size_t)N * 32;  // conv2 xl
  u16* B2 = (u16*)(W + o); o += (size_t)N * 32;  // conv2 xr
  float* Hc  = W + o; o += (size_t)N * 64;   // conv1 state / final h
  float* F0  = W + o; o += (size_t)N * 64;   // nf0 (conv2 pre)
  float* Fc  = W + o; o += (size_t)N * 64;   // conv2 state / final nf
  float* XF  = W + o; o += (size_t)S * 448;  // xf [S,448]
  float* XFG = W + o; o += (size_t)S * 64;
  float* Y   = W + o; o += (size_t)S * 64;
  float* Y2  = W + o; o += (size_t)S * 64;
  float* WEC = W + o; o += 6 * 1024;
  float* BEC = W + o; o += 6 * 64;
  float* val2s = W + o; o += E;
  float* val3s = W + o; o += E;
  float* val4s = W + o; o += NNZSS;
  // CSR int arrays
  int* I = (int*)(W + o);
  size_t q = 0;
  int* cur1 = I + q; q += N + 1;
  int* cur2 = I + q; q += S + 1;
  int* cur3 = I + q; q += S + 1;
  int* cur4 = I + q; q += S + 1;
  int* rp1  = I + q; q += N + 1;
  int* rp2  = I + q; q += S + 1;
  int* rp3  = I + q; q += S + 1;
  int* rp4  = I + q; q += S + 1;
  int* eid1 = I + q; q += E;
  int* src1s = I + q; q += E;
  int* col2s = I + q; q += E;
  int* col3s = I + q; q += E;
  int* src4s = I + q; q += NNZSS;
  int* bs1  = I + q; q += 256;
  int* bs2  = I + q; q += 256;
  int* bs3  = I + q; q += 256;
  int* bs4  = I + q; q += 256;

  const int* edst = edge_index + E;

  dim3 blk(256);
  const int gN64 = (N + 63) / 64;
  const int gS64 = (S + 63) / 64;
  const int gN4  = (N + 3) / 4;
  const int gS4  = (S + 3) / 4;
  const int nbN  = (N + 1 + 1023) / 1024;
  const int nbS  = (S + 1 + 1023) / 1024;

  // ---- CSR builds ----
  long ztot = (long)(N + 1) + 3L * (S + 1);
  fill_zero<<<256, blk, 0, stream>>>((float*)cur1, ztot);
  hist_k<<<512, blk, 0, stream>>>(edst,   E,     cur1);
  hist_k<<<512, blk, 0, stream>>>(se_row, E,     cur2);
  hist_k<<<512, blk, 0, stream>>>(sn_row, E,     cur3);
  hist_k<<<512, blk, 0, stream>>>(ss_col, NNZSS, cur4);

  scan_p1<<<nbN, blk, 0, stream>>>(cur1, N + 1, bs1);
  scan_p1<<<nbS, blk, 0, stream>>>(cur2, S + 1, bs2);
  scan_p1<<<nbS, blk, 0, stream>>>(cur3, S + 1, bs3);
  scan_p1<<<nbS, blk, 0, stream>>>(cur4, S + 1, bs4);
  scan_p2<<<1, blk, 0, stream>>>(bs1, nbN, rp1, N);
  scan_p2<<<1, blk, 0, stream>>>(bs2, nbS, rp2, S);
  scan_p2<<<1, blk, 0, stream>>>(bs3, nbS, rp3, S);
  scan_p2<<<1, blk, 0, stream>>>(bs4, nbS, rp4, S);
  scan_p3<<<nbN, blk, 0, stream>>>(cur1, N, bs1, rp1, cur1);
  scan_p3<<<nbS, blk, 0, stream>>>(cur2, S, bs2, rp2, cur2);
  scan_p3<<<nbS, blk, 0, stream>>>(cur3, S, bs3, rp3, cur3);
  scan_p3<<<nbS, blk, 0, stream>>>(cur4, S, bs4, rp4, cur4);

  scat_pair_k<<<512, blk, 0, stream>>>(edst,   edge_index, nullptr, E,     cur1, src1s, nullptr, eid1);
  scat_pair_k<<<512, blk, 0, stream>>>(se_row, se_col,     se_val,  E,     cur2, col2s, val2s, nullptr);
  scat_pair_k<<<512, blk, 0, stream>>>(sn_row, sn_col,     sn_val,  E,     cur3, col3s, val3s, nullptr);
  scat_pair_k<<<512, blk, 0, stream>>>(ss_col, ss_row,     ss_val,  NNZSS, cur4, src4s, val4s, nullptr);

  // composed edge-projection weights
  compose_we<<<6, blk, 0, stream>>>((const float*)d_in[12], (const float*)d_in[13],
                                    (const float*)d_in[20], (const float*)d_in[27], WEC, BEC);

  // nf0 = gelu(x_rec @ node_lin_W + b)   (K=32)
  gemm_tile<1, false, false><<<gN64, blk, 0, stream>>>(x_rec, N, 32, node_lin_W, node_lin_b, F0,
                                                       nullptr, nullptr, nullptr);

  // fused conv1+conv2 stacks (pre1 = node_embed, pre2 = F0)
  const float* st1 = node_embed;
  const float* st2 = F0;
  for (int l = 0; l < 3; ++l) {
    gemm_tile<0, true, true><<<gN64, blk, 0, stream>>>(st1, N, 64,
        c1_Wl + l * 4096, c1_bl + l * 64, A, c1_Wr + l * 4096, c1_br + l * 64, B);
    gemm_tile<0, true, true><<<gN64, blk, 0, stream>>>(st2, N, 64,
        c2_Wl + l * 4096, c2_bl + l * 64, A2, c2_Wr + l * 4096, c2_br + l * 64, B2);
    gat_gather2<<<gN4, blk, 0, stream>>>(rp1, eid1, src1s, attr,
        WEC + l * 1024, BEC + l * 64, c1_att + l * 64, c1_bias + l * 64,
        WEC + (3 + l) * 1024, BEC + (3 + l) * 64, c2_att + l * 64, c2_bias + l * 64,
        A, B, node_embed, Hc,
        A2, B2, F0, Fc, N);
    st1 = Hc;
    st2 = Fc;
  }

  // xf assembly
  xf_init<<<((long)S * 192 + 255) / 256, blk, 0, stream>>>(XF, seg_embed, time_embed, week_embed,
                                                           cur_t, cur_w, S);
  spmm_se_g<<<gS4, blk, 0, stream>>>(rp2, col2s, val2s, edge_embed, attr,
                                     attr2_W, attr2_b, XF, S);
  spmm_sn_g<<<gS4, blk, 0, stream>>>(rp3, col3s, val3s, Hc, Fc, XF, S);

  // conv3 on segment graph (K=448), bf16 xl3/xr3
  gemm_tile<0, true, true><<<gS64, blk, 0, stream>>>(XF, S, 448, c3_Wl, c3_bl, A, c3_Wr, c3_br, B);
  gat_seg_g<<<gS4, blk, 0, stream>>>(rp4, src4s, val4s, c3_We, c3_att, c3_bias,
                                     A, B, XFG, S);

  // MLP head
  gemm_tile<1, false, false><<<gS64, blk, 0, stream>>>(XF, S, 448, lin1_W, lin1_b, Y,
                                                       nullptr, nullptr, nullptr);
  gemm_tile<1, false, false><<<gS64, blk, 0, stream>>>(Y, S, 64, lin2_W, lin2_b, Y2,
                                                       nullptr, nullptr, nullptr);
  head_k<<<gS4, blk, 0, stream>>>(Y2, XFG, out_W, out_b, (float*)d_out, S);
}

// Round 6
// 794.181 us; speedup vs baseline: 2.3278x; 1.4205x over previous
//
#include <hip/hip_runtime.h>
#include <hip/hip_bf16.h>
#include <math.h>

#define DEV __device__ __forceinline__
typedef unsigned short u16;
typedef unsigned int u32;
typedef __attribute__((ext_vector_type(8))) short bf16x8;
typedef __attribute__((ext_vector_type(4))) float f32x4;

DEV float gelu_f(float x) { return 0.5f * x * (1.f + erff(x * 0.70710678118654752f)); }
DEV int rfl(int v) { return __builtin_amdgcn_readfirstlane(v); }
DEV float rflf(float v) {
  int i = __builtin_amdgcn_readfirstlane(__float_as_int(v));
  return __int_as_float(i);
}
DEV u16 f2b(float x) { __hip_bfloat16 h = __float2bfloat16(x); return *reinterpret_cast<u16*>(&h); }
DEV float b2f(u16 u) { __hip_bfloat16 h; *reinterpret_cast<u16*>(&h) = u; return __bfloat162float(h); }
DEV u32 pack2(float a, float b) { return (u32)f2b(a) | ((u32)f2b(b) << 16); }

// ---------------- zero fill ----------------
__global__ void fill_zero(float* __restrict__ p, long n) {
  long i = (long)blockIdx.x * blockDim.x + threadIdx.x;
  long st = (long)gridDim.x * blockDim.x;
  for (; i < n; i += st) p[i] = 0.f;
}

// ---------------- CSR build: histogram ----------------
__global__ void hist_k(const int* __restrict__ key, int n, int* __restrict__ cnt) {
  int i = blockIdx.x * blockDim.x + threadIdx.x;
  int st = gridDim.x * blockDim.x;
  for (; i < n; i += st) atomicAdd(&cnt[key[i]], 1);
}

// ---------------- multi-block exclusive scan ----------------
__global__ __launch_bounds__(256) void scan_p1(const int* __restrict__ cnt, int n,
                                               int* __restrict__ bsum) {
  __shared__ int ts[256];
  int base = blockIdx.x * 1024;
  int s = 0;
  #pragma unroll
  for (int k = 0; k < 4; ++k) {
    int g = base + threadIdx.x * 4 + k;
    if (g < n) s += cnt[g];
  }
  ts[threadIdx.x] = s;
  __syncthreads();
  for (int d = 128; d; d >>= 1) {
    if (threadIdx.x < d) ts[threadIdx.x] += ts[threadIdx.x + d];
    __syncthreads();
  }
  if (threadIdx.x == 0) bsum[blockIdx.x] = ts[0];
}

__global__ __launch_bounds__(256) void scan_p2(int* __restrict__ bsum, int nb,
                                               int* __restrict__ rp, int n) {
  __shared__ int ts[256];
  int tid = threadIdx.x;
  int v = (tid < nb) ? bsum[tid] : 0;
  ts[tid] = v;
  __syncthreads();
  for (int d = 1; d < 256; d <<= 1) {
    int w = (tid >= d) ? ts[tid - d] : 0;
    __syncthreads();
    ts[tid] += w;
    __syncthreads();
  }
  if (tid < nb) bsum[tid] = (tid == 0) ? 0 : ts[tid - 1];
  if (tid == 255) rp[n] = ts[255];
}

__global__ __launch_bounds__(256) void scan_p3(const int* __restrict__ cnt, int n,
                                               const int* __restrict__ bsum,
                                               int* __restrict__ rp, int* __restrict__ cursor) {
  __shared__ int ts[256];
  int base = blockIdx.x * 1024;
  int tid = threadIdx.x;
  int c[4];
  int s = 0;
  #pragma unroll
  for (int k = 0; k < 4; ++k) {
    int g = base + tid * 4 + k;
    c[k] = (g < n) ? cnt[g] : 0;
    s += c[k];
  }
  ts[tid] = s;
  __syncthreads();
  for (int d = 1; d < 256; d <<= 1) {
    int w = (tid >= d) ? ts[tid - d] : 0;
    __syncthreads();
    ts[tid] += w;
    __syncthreads();
  }
  int run = bsum[blockIdx.x] + ((tid == 0) ? 0 : ts[tid - 1]);
  #pragma unroll
  for (int k = 0; k < 4; ++k) {
    int g = base + tid * 4 + k;
    if (g < n) {
      rp[g] = run;
      cursor[g] = run;
      run += c[k];
    }
  }
}

// ---------------- CSR build: scatter (payload-carrying) ----------------
__global__ void scat_pair_k(const int* __restrict__ key, const int* __restrict__ aux,
                            const float* __restrict__ val, int n,
                            int* __restrict__ cursor, int* __restrict__ auxs,
                            float* __restrict__ vals, int* __restrict__ eids) {
  int i = blockIdx.x * blockDim.x + threadIdx.x;
  int st = gridDim.x * blockDim.x;
  for (; i < n; i += st) {
    int p = atomicAdd(&cursor[key[i]], 1);
    auxs[p] = aux[i];
    if (vals) vals[p] = val[i];
    if (eids) eids[p] = i;
  }
}

// ---------------- compose We' = attr1_W @ We[l], be' = attr1_b @ We[l] ----------------
__global__ __launch_bounds__(256) void compose_we(
    const float* __restrict__ a1W, const float* __restrict__ a1b,
    const float* __restrict__ c1We, const float* __restrict__ c2We,
    float* __restrict__ WEC, float* __restrict__ BEC)
{
  int l = blockIdx.x;
  const float* We = (l < 3) ? (c1We + l * 4096) : (c2We + (l - 3) * 4096);
  __shared__ float wes[4096];
  int tid = threadIdx.x;
  for (int i = tid; i < 4096; i += 256) wes[i] = We[i];
  __syncthreads();
  for (int i = tid; i < 1024; i += 256) {
    int k = i >> 6, j = i & 63;
    float s = 0.f;
    #pragma unroll 16
    for (int m = 0; m < 64; ++m) s += a1W[k * 64 + m] * wes[m * 64 + j];
    WEC[l * 1024 + i] = s;
  }
  if (tid < 64) {
    float s = 0.f;
    for (int m = 0; m < 64; ++m) s += a1b[m] * wes[m * 64 + tid];
    BEC[l * 64 + tid] = s;
  }
}

// ---------------- weight prep: transpose + bf16 ([K][64] fp32 -> [64][K] bf16) ----------
// WTS layout (u16 elems):
//  c1l 3x4096 @0 | c1r @12288 | c2l @24576 | c2r @36864 | node(K=32) @49152
//  c3l(K=448) @51200 | c3r @79872 | lin1 @108544 | lin2(K=64) @137216 | end 141312
__global__ __launch_bounds__(256) void prep_wt(
    const float* __restrict__ c1Wl, const float* __restrict__ c1Wr,
    const float* __restrict__ c2Wl, const float* __restrict__ c2Wr,
    const float* __restrict__ nodeW, const float* __restrict__ c3Wl,
    const float* __restrict__ c3Wr, const float* __restrict__ lin1W,
    const float* __restrict__ lin2W, u16* __restrict__ WTS)
{
  long idx = (long)blockIdx.x * 256 + threadIdx.x;
  if (idx >= 141312) return;
  float v;
  if (idx < 49152) {            // 4 groups of 3 matrices, K=64
    const float* src = (idx < 12288) ? c1Wl : (idx < 24576) ? c1Wr : (idx < 36864) ? c2Wl : c2Wr;
    long loc = idx & 12287;     // within group (12288 = 3*4096)
    long m = loc >> 12;         // matrix in group
    int c = (int)((loc >> 6) & 63), k = (int)(loc & 63);
    v = src[m * 4096 + k * 64 + c];
  } else if (idx < 51200) {     // node, K=32
    long loc = idx - 49152;
    int c = (int)(loc >> 5), k = (int)(loc & 31);
    v = nodeW[k * 64 + c];
  } else if (idx < 137216) {    // K=448: c3l, c3r, lin1
    long base = (idx < 79872) ? 51200 : (idx < 108544) ? 79872 : 108544;
    const float* src = (idx < 79872) ? c3Wl : (idx < 108544) ? c3Wr : lin1W;
    long loc = idx - base;
    int c = (int)(loc / 448), k = (int)(loc % 448);
    v = src[k * 64 + c];
  } else {                      // lin2, K=64
    long loc = idx - 137216;
    int c = (int)(loc >> 6), k = (int)(loc & 63);
    v = lin2W[k * 64 + c];
  }
  WTS[idx] = f2b(v);
}

// ---------------- MFMA GEMM: O = act(X@W + b), 64 out cols, optional pair ----------------
// block 256 = 4 waves; tile 64 rows x 64 cols; K-chunks of 64; bf16 MFMA, fp32 acc.
// LDS XOR-swizzle (granule ^= row&7) on both write and read -> conflict-free ds_read_b128.
template <int ACT, bool PAIR, bool XBF, bool OBF>
__global__ __launch_bounds__(256) void gemm_mfma(
    const void* __restrict__ Xv, int nrows, int K,
    const u16* __restrict__ WT1, const float* __restrict__ b1, void* __restrict__ O1v,
    const u16* __restrict__ WT2, const float* __restrict__ b2, void* __restrict__ O2v)
{
  __shared__ __align__(16) u16 xs[4096];
  __shared__ __align__(16) u16 ws1[4096];
  __shared__ __align__(16) u16 ws2[PAIR ? 4096 : 8];

  const int tid = threadIdx.x;
  const int row0 = blockIdx.x * 64;
  const int wid = tid >> 6, lane = tid & 63;
  const int lrow = lane & 15, lgrp = lane >> 4;
  const int r0 = wid * 16;
  const int sr = tid >> 2;   // staging row/col 0..63
  const int sq = tid & 3;    // staging quarter (16 k-elems)
  const int ssw = sr & 7;

  f32x4 acc[4];
  f32x4 acc2[PAIR ? 4 : 1];
  #pragma unroll
  for (int f = 0; f < 4; ++f) { acc[f] = (f32x4)0.f; if constexpr (PAIR) acc2[f] = (f32x4)0.f; }

  for (int kc = 0; kc < K; kc += 64) {
    __syncthreads();
    // ---- stage X (convert to bf16 if fp32) ----
    {
      int gr = row0 + sr;
      int kb = kc + sq * 16;
      uint4 pa, pb;
      if constexpr (XBF) {
        const u16* X = (const u16*)Xv;
        if (gr < nrows && kb + 16 <= K) {
          pa = *(const uint4*)&X[(size_t)gr * K + kb];
          pb = *(const uint4*)&X[(size_t)gr * K + kb + 8];
        } else {
          u32 p[8];
          #pragma unroll
          for (int i = 0; i < 8; ++i) {
            u16 a = (gr < nrows && kb + 2 * i < K)     ? X[(size_t)gr * K + kb + 2 * i]     : (u16)0;
            u16 b = (gr < nrows && kb + 2 * i + 1 < K) ? X[(size_t)gr * K + kb + 2 * i + 1] : (u16)0;
            p[i] = (u32)a | ((u32)b << 16);
          }
          pa = make_uint4(p[0], p[1], p[2], p[3]);
          pb = make_uint4(p[4], p[5], p[6], p[7]);
        }
      } else {
        const float* X = (const float*)Xv;
        float f[16];
        if (gr < nrows && kb + 16 <= K) {
          #pragma unroll
          for (int i = 0; i < 4; ++i)
            *(float4*)&f[i * 4] = *(const float4*)&X[(size_t)gr * K + kb + i * 4];
        } else {
          #pragma unroll
          for (int i = 0; i < 16; ++i)
            f[i] = (gr < nrows && kb + i < K) ? X[(size_t)gr * K + kb + i] : 0.f;
        }
        u32 p[8];
        #pragma unroll
        for (int i = 0; i < 8; ++i) p[i] = pack2(f[2 * i], f[2 * i + 1]);
        pa = make_uint4(p[0], p[1], p[2], p[3]);
        pb = make_uint4(p[4], p[5], p[6], p[7]);
      }
      *(uint4*)&xs[sr * 64 + (((sq * 2))     ^ ssw) * 8] = pa;
      *(uint4*)&xs[sr * 64 + (((sq * 2 + 1)) ^ ssw) * 8] = pb;
    }
    // ---- stage WT (already bf16, [64][K]) ----
    {
      int kb = kc + sq * 16;
      uint4 qa, qb;
      if (kb + 16 <= K) {
        qa = *(const uint4*)&WT1[(size_t)sr * K + kb];
        qb = *(const uint4*)&WT1[(size_t)sr * K + kb + 8];
      } else {
        u32 p[8];
        #pragma unroll
        for (int i = 0; i < 8; ++i) {
          u16 a = (kb + 2 * i < K)     ? WT1[(size_t)sr * K + kb + 2 * i]     : (u16)0;
          u16 b = (kb + 2 * i + 1 < K) ? WT1[(size_t)sr * K + kb + 2 * i + 1] : (u16)0;
          p[i] = (u32)a | ((u32)b << 16);
        }
        qa = make_uint4(p[0], p[1], p[2], p[3]);
        qb = make_uint4(p[4], p[5], p[6], p[7]);
      }
      *(uint4*)&ws1[sr * 64 + (((sq * 2))     ^ ssw) * 8] = qa;
      *(uint4*)&ws1[sr * 64 + (((sq * 2 + 1)) ^ ssw) * 8] = qb;
      if constexpr (PAIR) {
        if (kb + 16 <= K) {
          qa = *(const uint4*)&WT2[(size_t)sr * K + kb];
          qb = *(const uint4*)&WT2[(size_t)sr * K + kb + 8];
        } else {
          u32 p[8];
          #pragma unroll
          for (int i = 0; i < 8; ++i) {
            u16 a = (kb + 2 * i < K)     ? WT2[(size_t)sr * K + kb + 2 * i]     : (u16)0;
            u16 b = (kb + 2 * i + 1 < K) ? WT2[(size_t)sr * K + kb + 2 * i + 1] : (u16)0;
            p[i] = (u32)a | ((u32)b << 16);
          }
          qa = make_uint4(p[0], p[1], p[2], p[3]);
          qb = make_uint4(p[4], p[5], p[6], p[7]);
        }
        *(uint4*)&ws2[sr * 64 + (((sq * 2))     ^ ssw) * 8] = qa;
        *(uint4*)&ws2[sr * 64 + (((sq * 2 + 1)) ^ ssw) * 8] = qb;
      }
    }
    __syncthreads();
    // ---- MFMA ----
    #pragma unroll
    for (int kh = 0; kh < 2; ++kh) {
      const int g = (4 * kh + lgrp) ^ (lrow & 7);
      bf16x8 a = *(const bf16x8*)&xs[(r0 + lrow) * 64 + g * 8];
      #pragma unroll
      for (int f = 0; f < 4; ++f) {
        int col = f * 16 + lrow;
        bf16x8 b = *(const bf16x8*)&ws1[col * 64 + g * 8];
        acc[f] = __builtin_amdgcn_mfma_f32_16x16x32_bf16(a, b, acc[f], 0, 0, 0);
        if constexpr (PAIR) {
          bf16x8 b2v = *(const bf16x8*)&ws2[col * 64 + g * 8];
          acc2[f] = __builtin_amdgcn_mfma_f32_16x16x32_bf16(a, b2v, acc2[f], 0, 0, 0);
        }
      }
    }
  }

  // ---- epilogue: bias (+act) + store; C/D: col=lane&15, row=4*(lane>>4)+reg ----
  #pragma unroll
  for (int f = 0; f < 4; ++f) {
    int col = f * 16 + lrow;
    float bv = b1[col];
    float bv2 = 0.f;
    if constexpr (PAIR) bv2 = b2[col];
    #pragma unroll
    for (int r = 0; r < 4; ++r) {
      int grow = row0 + r0 + lgrp * 4 + r;
      if (grow >= nrows) continue;
      float v = acc[f][r] + bv;
      if constexpr (ACT == 1) v = gelu_f(v);
      if constexpr (OBF) ((u16*)O1v)[(size_t)grow * 64 + col] = f2b(v);
      else               ((float*)O1v)[(size_t)grow * 64 + col] = v;
      if constexpr (PAIR) {
        float v2 = acc2[f][r] + bv2;
        if constexpr (ACT == 1) v2 = gelu_f(v2);
        if constexpr (OBF) ((u16*)O2v)[(size_t)grow * 64 + col] = f2b(v2);
        else               ((float*)O2v)[(size_t)grow * 64 + col] = v2;
      }
    }
  }
}

// ---------------- fused dual-conv gather GATv2 layer (bf16 state, 2x edge unroll) ----------
__global__ __launch_bounds__(256) void gat_gather2(
    const int* __restrict__ rowptr, const int* __restrict__ eids,
    const int* __restrict__ srcs, const float* __restrict__ attr,
    const float* __restrict__ wec1, const float* __restrict__ bec1,
    const float* __restrict__ att1, const float* __restrict__ bias1,
    const float* __restrict__ wec2, const float* __restrict__ bec2,
    const float* __restrict__ att2, const float* __restrict__ bias2,
    const u16* __restrict__ xl1, const u16* __restrict__ xr1,
    const float* __restrict__ pre1, u16* __restrict__ out1,
    const u16* __restrict__ xl2, const u16* __restrict__ xr2,
    const u16* __restrict__ pre2, u16* __restrict__ out2, int n)
{
  int tid = threadIdx.x;
  int wid = tid >> 6, lane = tid & 63;
  int d = blockIdx.x * 4 + wid;
  if (d >= n) return;
  float w1[16], w2[16];
  #pragma unroll
  for (int k = 0; k < 16; ++k) {
    w1[k] = wec1[k * 64 + lane];
    w2[k] = wec2[k * 64 + lane];
  }
  float be1 = bec1[lane], be2 = bec2[lane];
  float at1 = att1[lane], at2 = att2[lane];
  float xr1v = b2f(xr1[(size_t)d * 64 + lane]);
  float xr2v = b2f(xr2[(size_t)d * 64 + lane]);
  float n1 = 0.f, d1 = 0.f, n2 = 0.f, d2 = 0.f;
  int j0 = rfl(rowptr[d]), j1 = rfl(rowptr[d + 1]);
  int j = j0;
  for (; j + 2 <= j1; j += 2) {
    int ea = rfl(eids[j]),     sa = rfl(srcs[j]);
    int eb = rfl(eids[j + 1]), sb = rfl(srcs[j + 1]);
    const float* ara = attr + (size_t)ea * 16;
    const float* arb = attr + (size_t)eb * 16;
    float xl1a = b2f(xl1[(size_t)sa * 64 + lane]);
    float xl2a = b2f(xl2[(size_t)sa * 64 + lane]);
    float xl1b = b2f(xl1[(size_t)sb * 64 + lane]);
    float xl2b = b2f(xl2[(size_t)sb * 64 + lane]);
    float ep1a = be1, ep2a = be2, ep1b = be1, ep2b = be2;
    #pragma unroll
    for (int k = 0; k < 16; ++k) {
      float aka = ara[k], akb = arb[k];
      ep1a += aka * w1[k]; ep2a += aka * w2[k];
      ep1b += akb * w1[k]; ep2b += akb * w2[k];
    }
    float m1a = xl1a + xr1v + ep1a, m2a = xl2a + xr2v + ep2a;
    float m1b = xl1b + xr1v + ep1b, m2b = xl2b + xr2v + ep2b;
    float l1a = m1a < 0.f ? 0.2f * m1a : m1a;
    float l2a = m2a < 0.f ? 0.2f * m2a : m2a;
    float l1b = m1b < 0.f ? 0.2f * m1b : m1b;
    float l2b = m2b < 0.f ? 0.2f * m2b : m2b;
    float t1a = at1 * l1a, t2a = at2 * l2a, t1b = at1 * l1b, t2b = at2 * l2b;
    #pragma unroll
    for (int o = 32; o; o >>= 1) {
      t1a += __shfl_xor(t1a, o, 64);
      t2a += __shfl_xor(t2a, o, 64);
      t1b += __shfl_xor(t1b, o, 64);
      t2b += __shfl_xor(t2b, o, 64);
    }
    float x1a = __expf(t1a), x2a = __expf(t2a), x1b = __expf(t1b), x2b = __expf(t2b);
    n1 += x1a * xl1a + x1b * xl1b; d1 += x1a + x1b;
    n2 += x2a * xl2a + x2b * xl2b; d2 += x2a + x2b;
  }
  for (; j < j1; ++j) {
    int e = rfl(eids[j]);
    int s = rfl(srcs[j]);
    const float* arow = attr + (size_t)e * 16;
    float xl1v = b2f(xl1[(size_t)s * 64 + lane]);
    float xl2v = b2f(xl2[(size_t)s * 64 + lane]);
    float ep1 = be1, ep2 = be2;
    #pragma unroll
    for (int k = 0; k < 16; ++k) {
      float ak = arow[k];
      ep1 += ak * w1[k];
      ep2 += ak * w2[k];
    }
    float m1 = xl1v + xr1v + ep1;
    float m2 = xl2v + xr2v + ep2;
    float lr1 = m1 < 0.f ? 0.2f * m1 : m1;
    float lr2 = m2 < 0.f ? 0.2f * m2 : m2;
    float t1 = at1 * lr1, t2 = at2 * lr2;
    #pragma unroll
    for (int o = 32; o; o >>= 1) {
      t1 += __shfl_xor(t1, o, 64);
      t2 += __shfl_xor(t2, o, 64);
    }
    float ex1 = __expf(t1), ex2 = __expf(t2);
    n1 += ex1 * xl1v; d1 += ex1;
    n2 += ex2 * xl2v; d2 += ex2;
  }
  size_t base = (size_t)d * 64 + lane;
  float v1 = n1 / (d1 + 1e-16f) + bias1[lane];
  float v2 = n2 / (d2 + 1e-16f) + bias2[lane];
  out1[base] = f2b(gelu_f(v1) + pre1[base]);
  out2[base] = f2b(gelu_f(v2) + b2f(pre2[base]));
}

// ---------------- fused gather GATv2 (segment graph, edge_dim=1, bf16 xl/xr) ----------------
__global__ __launch_bounds__(256) void gat_seg_g(
    const int* __restrict__ rowptr, const int* __restrict__ srcs,
    const float* __restrict__ vals,
    const float* __restrict__ we3, const float* __restrict__ att,
    const float* __restrict__ bias,
    const u16* __restrict__ xl, const u16* __restrict__ xr,
    float* __restrict__ out, int n)
{
  int tid = threadIdx.x;
  int wid = tid >> 6, lane = tid & 63;
  int d = blockIdx.x * 4 + wid;
  if (d >= n) return;
  float we3v = we3[lane], attv = att[lane], bsv = bias[lane];
  float xrv = b2f(xr[(size_t)d * 64 + lane]);
  float accn = 0.f, accd = 0.f;
  int j0 = rfl(rowptr[d]), j1 = rfl(rowptr[d + 1]);
  for (int j = j0; j < j1; ++j) {
    int s = rfl(srcs[j]);
    float vv = rflf(vals[j]);
    float ep = vv * we3v;
    float xlv = b2f(xl[(size_t)s * 64 + lane]);
    float m = xlv + xrv + ep;
    float lr = m < 0.f ? 0.2f * m : m;
    float t = attv * lr;
    #pragma unroll
    for (int o = 32; o; o >>= 1) t += __shfl_xor(t, o, 64);
    float ex = __expf(t);
    accn += ex * xlv;
    accd += ex;
  }
  float v = accn / (accd + 1e-16f) + bsv;
  out[(size_t)d * 64 + lane] = gelu_f(v);
}

// ---------------- xf partial init ----------------
__global__ void xf_init(
    float* __restrict__ xf, const float* __restrict__ seg_embed,
    const float* __restrict__ time_embed, const float* __restrict__ week_embed,
    const int* __restrict__ cur_t, const int* __restrict__ cur_w, int S)
{
  long idx = (long)blockIdx.x * blockDim.x + threadIdx.x;
  if (idx >= (long)S * 192) return;
  int s = idx / 192, c = idx % 192;
  if (c < 64)       xf[(size_t)s * 448 + c]       = seg_embed[(size_t)s * 64 + c];
  else if (c < 128) xf[(size_t)s * 448 + 256 + c] = time_embed[cur_t[0] * 64 + (c - 64)];
  else              xf[(size_t)s * 448 + 256 + c] = week_embed[cur_w[0] * 64 + (c - 128)];
}

// ---------------- gather spmm se ----------------
__global__ __launch_bounds__(256) void spmm_se_g(
    const int* __restrict__ rowptr, const int* __restrict__ cols,
    const float* __restrict__ vals,
    const float* __restrict__ edge_embed, const float* __restrict__ attr,
    const float* __restrict__ W2, const float* __restrict__ b2,
    float* __restrict__ xf, int S)
{
  __shared__ float ws[1024];
  __shared__ float bs[64];
  int tid = threadIdx.x;
  for (int i = tid; i < 1024; i += 256) ws[i] = W2[i];
  if (tid < 64) bs[tid] = b2[tid];
  __syncthreads();
  int wid = tid >> 6, lane = tid & 63;
  int s = blockIdx.x * 4 + wid;
  if (s >= S) return;
  float acc1 = 0.f, aat = 0.f, vs = 0.f;
  int j0 = rfl(rowptr[s]), j1 = rfl(rowptr[s + 1]);
  for (int j = j0; j < j1; ++j) {
    int c = rfl(cols[j]);
    float v = rflf(vals[j]);
    acc1 += v * edge_embed[(size_t)c * 64 + lane];
    aat  += v * attr[(size_t)c * 16 + (lane & 15)];
    vs   += v;
  }
  float x2 = vs * bs[lane];
  #pragma unroll
  for (int k = 0; k < 16; ++k)
    x2 += __shfl(aat, k, 64) * ws[k * 64 + lane];
  xf[(size_t)s * 448 + 64 + lane]  = acc1;
  xf[(size_t)s * 448 + 128 + lane] = x2;
}

// ---------------- gather spmm sn (bf16 h/nf) ----------------
__global__ __launch_bounds__(256) void spmm_sn_g(
    const int* __restrict__ rowptr, const int* __restrict__ cols,
    const float* __restrict__ vals,
    const u16* __restrict__ h, const u16* __restrict__ nf,
    float* __restrict__ xf, int S)
{
  int tid = threadIdx.x;
  int wid = tid >> 6, lane = tid & 63;
  int s = blockIdx.x * 4 + wid;
  if (s >= S) return;
  float acch = 0.f, accf = 0.f;
  int j0 = rfl(rowptr[s]), j1 = rfl(rowptr[s + 1]);
  for (int j = j0; j < j1; ++j) {
    int c = rfl(cols[j]);
    float v = rflf(vals[j]);
    acch += v * b2f(h[(size_t)c * 64 + lane]);
    accf += v * b2f(nf[(size_t)c * 64 + lane]);
  }
  xf[(size_t)s * 448 + 192 + lane] = acch;
  xf[(size_t)s * 448 + 256 + lane] = accf;
}

// ---------------- head ----------------
__global__ __launch_bounds__(256) void head_k(
    const float* __restrict__ y2, const float* __restrict__ xfg,
    const float* __restrict__ outW, const float* __restrict__ outb,
    float* __restrict__ out, int S)
{
  int wid = threadIdx.x >> 6, lane = threadIdx.x & 63;
  int s = blockIdx.x * 4 + wid;
  if (s >= S) return;
  float t = y2[(size_t)s * 64 + lane] * outW[lane] + xfg[(size_t)s * 64 + lane] * outW[64 + lane];
  #pragma unroll
  for (int o = 32; o; o >>= 1) t += __shfl_xor(t, o, 64);
  if (lane == 0) {
    float z = t + outb[0];
    out[s] = 3600.f / (1.f + __expf(-z));
  }
}

extern "C" void kernel_launch(void* const* d_in, const int* in_sizes, int n_in,
                              void* d_out, int out_size, void* d_ws, size_t ws_size,
                              hipStream_t stream)
{
  const float* x_rec       = (const float*)d_in[0];
  const float* attr        = (const float*)d_in[1];
  const float* se_val      = (const float*)d_in[2];
  const float* sn_val      = (const float*)d_in[3];
  const float* ss_val      = (const float*)d_in[4];
  const float* node_embed  = (const float*)d_in[5];
  const float* edge_embed  = (const float*)d_in[6];
  const float* seg_embed   = (const float*)d_in[7];
  const float* time_embed  = (const float*)d_in[8];
  const float* week_embed  = (const float*)d_in[9];
  const float* node_lin_W  = (const float*)d_in[10];
  const float* node_lin_b  = (const float*)d_in[11];
  const float* attr2_W     = (const float*)d_in[14];
  const float* attr2_b     = (const float*)d_in[15];
  const float* c1_Wl       = (const float*)d_in[16];
  const float* c1_bl       = (const float*)d_in[17];
  const float* c1_Wr       = (const float*)d_in[18];
  const float* c1_br       = (const float*)d_in[19];
  const float* c1_att      = (const float*)d_in[21];
  const float* c1_bias     = (const float*)d_in[22];
  const float* c2_Wl       = (const float*)d_in[23];
  const float* c2_bl       = (const float*)d_in[24];
  const float* c2_Wr       = (const float*)d_in[25];
  const float* c2_br       = (const float*)d_in[26];
  const float* c2_att      = (const float*)d_in[28];
  const float* c2_bias     = (const float*)d_in[29];
  const float* c3_Wl       = (const float*)d_in[30];
  const float* c3_bl       = (const float*)d_in[31];
  const float* c3_Wr       = (const float*)d_in[32];
  const float* c3_br       = (const float*)d_in[33];
  const float* c3_We       = (const float*)d_in[34];
  const float* c3_att      = (const float*)d_in[35];
  const float* c3_bias     = (const float*)d_in[36];
  const float* lin1_W      = (const float*)d_in[37];
  const float* lin1_b      = (const float*)d_in[38];
  const float* lin2_W      = (const float*)d_in[39];
  const float* lin2_b      = (const float*)d_in[40];
  const float* out_W       = (const float*)d_in[41];
  const float* out_b       = (const float*)d_in[42];
  const int* edge_index    = (const int*)d_in[43];
  const int* se_row        = (const int*)d_in[44];
  const int* se_col        = (const int*)d_in[45];
  const int* sn_row        = (const int*)d_in[46];
  const int* sn_col        = (const int*)d_in[47];
  const int* ss_row        = (const int*)d_in[48];
  const int* ss_col        = (const int*)d_in[49];
  const int* cur_t         = (const int*)d_in[50];
  const int* cur_w         = (const int*)d_in[51];

  const int N = in_sizes[0] / 32;
  const int E = in_sizes[1] / 16;
  const int S = in_sizes[7] / 64;
  const int NNZSS = in_sizes[4];

  // workspace layout (float units)
  float* W = (float*)d_ws;
  size_t o = 0;
  u16* A   = (u16*)(W + o); o += (size_t)N * 32;  // conv1 xl / conv3 xl
  u16* B   = (u16*)(W + o); o += (size_t)N * 32;  // conv1 xr / conv3 xr
  u16* A2  = (u16*)(W + o); o += (size_t)N * 32;  // conv2 xl
  u16* B2  = (u16*)(W + o); o += (size_t)N * 32;  // conv2 xr
  u16* Hc  = (u16*)(W + o); o += (size_t)N * 32;  // conv1 state / final h (bf16)
  u16* F0  = (u16*)(W + o); o += (size_t)N * 32;  // nf0 (bf16)
  u16* Fc  = (u16*)(W + o); o += (size_t)N * 32;  // conv2 state / final nf (bf16)
  float* XF  = W + o; o += (size_t)S * 448;       // xf [S,448]
  float* XFG = W + o; o += (size_t)S * 64;
  float* Y   = W + o; o += (size_t)S * 64;
  float* Y2  = W + o; o += (size_t)S * 64;
  float* WEC = W + o; o += 6 * 1024;
  float* BEC = W + o; o += 6 * 64;
  u16* WTS   = (u16*)(W + o); o += 70656;         // 141312 u16
  float* val2s = W + o; o += E;
  float* val3s = W + o; o += E;
  float* val4s = W + o; o += NNZSS;
  int* I = (int*)(W + o);
  size_t q = 0;
  int* cur1 = I + q; q += N + 1;
  int* cur2 = I + q; q += S + 1;
  int* cur3 = I + q; q += S + 1;
  int* cur4 = I + q; q += S + 1;
  int* rp1  = I + q; q += N + 1;
  int* rp2  = I + q; q += S + 1;
  int* rp3  = I + q; q += S + 1;
  int* rp4  = I + q; q += S + 1;
  int* eid1  = I + q; q += E;
  int* src1s = I + q; q += E;
  int* col2s = I + q; q += E;
  int* col3s = I + q; q += E;
  int* src4s = I + q; q += NNZSS;
  int* bs1  = I + q; q += 256;
  int* bs2  = I + q; q += 256;
  int* bs3  = I + q; q += 256;
  int* bs4  = I + q; q += 256;

  // WTS region pointers (must match prep_wt)
  u16* WT_c1l  = WTS;
  u16* WT_c1r  = WTS + 12288;
  u16* WT_c2l  = WTS + 24576;
  u16* WT_c2r  = WTS + 36864;
  u16* WT_node = WTS + 49152;
  u16* WT_c3l  = WTS + 51200;
  u16* WT_c3r  = WTS + 79872;
  u16* WT_lin1 = WTS + 108544;
  u16* WT_lin2 = WTS + 137216;

  const int* edst = edge_index + E;

  dim3 blk(256);
  const int gN64 = (N + 63) / 64;
  const int gS64 = (S + 63) / 64;
  const int gN4  = (N + 3) / 4;
  const int gS4  = (S + 3) / 4;
  const int nbN  = (N + 1 + 1023) / 1024;
  const int nbS  = (S + 1 + 1023) / 1024;

  // ---- CSR builds + weight prep ----
  long ztot = (long)(N + 1) + 3L * (S + 1);
  fill_zero<<<256, blk, 0, stream>>>((float*)cur1, ztot);
  prep_wt<<<(141312 + 255) / 256, blk, 0, stream>>>(c1_Wl, c1_Wr, c2_Wl, c2_Wr,
                                                    node_lin_W, c3_Wl, c3_Wr,
                                                    lin1_W, lin2_W, WTS);
  hist_k<<<512, blk, 0, stream>>>(edst,   E,     cur1);
  hist_k<<<512, blk, 0, stream>>>(se_row, E,     cur2);
  hist_k<<<512, blk, 0, stream>>>(sn_row, E,     cur3);
  hist_k<<<512, blk, 0, stream>>>(ss_col, NNZSS, cur4);

  scan_p1<<<nbN, blk, 0, stream>>>(cur1, N + 1, bs1);
  scan_p1<<<nbS, blk, 0, stream>>>(cur2, S + 1, bs2);
  scan_p1<<<nbS, blk, 0, stream>>>(cur3, S + 1, bs3);
  scan_p1<<<nbS, blk, 0, stream>>>(cur4, S + 1, bs4);
  scan_p2<<<1, blk, 0, stream>>>(bs1, nbN, rp1, N);
  scan_p2<<<1, blk, 0, stream>>>(bs2, nbS, rp2, S);
  scan_p2<<<1, blk, 0, stream>>>(bs3, nbS, rp3, S);
  scan_p2<<<1, blk, 0, stream>>>(bs4, nbS, rp4, S);
  scan_p3<<<nbN, blk, 0, stream>>>(cur1, N, bs1, rp1, cur1);
  scan_p3<<<nbS, blk, 0, stream>>>(cur2, S, bs2, rp2, cur2);
  scan_p3<<<nbS, blk, 0, stream>>>(cur3, S, bs3, rp3, cur3);
  scan_p3<<<nbS, blk, 0, stream>>>(cur4, S, bs4, rp4, cur4);

  scat_pair_k<<<512, blk, 0, stream>>>(edst,   edge_index, nullptr, E,     cur1, src1s, nullptr, eid1);
  scat_pair_k<<<512, blk, 0, stream>>>(se_row, se_col,     se_val,  E,     cur2, col2s, val2s, nullptr);
  scat_pair_k<<<512, blk, 0, stream>>>(sn_row, sn_col,     sn_val,  E,     cur3, col3s, val3s, nullptr);
  scat_pair_k<<<512, blk, 0, stream>>>(ss_col, ss_row,     ss_val,  NNZSS, cur4, src4s, val4s, nullptr);

  compose_we<<<6, blk, 0, stream>>>((const float*)d_in[12], (const float*)d_in[13],
                                    (const float*)d_in[20], (const float*)d_in[27], WEC, BEC);

  // nf0 = gelu(x_rec @ node_lin_W + b), K=32, bf16 out
  gemm_mfma<1, false, false, true><<<gN64, blk, 0, stream>>>(x_rec, N, 32, WT_node, node_lin_b, F0,
                                                             nullptr, nullptr, nullptr);

  // fused conv1+conv2 stacks (pre1 = node_embed fp32, pre2 = F0 bf16)
  for (int l = 0; l < 3; ++l) {
    if (l == 0)
      gemm_mfma<0, true, false, true><<<gN64, blk, 0, stream>>>(node_embed, N, 64,
          WT_c1l, c1_bl, A, WT_c1r, c1_br, B);
    else
      gemm_mfma<0, true, true, true><<<gN64, blk, 0, stream>>>(Hc, N, 64,
          WT_c1l + l * 4096, c1_bl + l * 64, A, WT_c1r + l * 4096, c1_br + l * 64, B);
    gemm_mfma<0, true, true, true><<<gN64, blk, 0, stream>>>(l == 0 ? F0 : Fc, N, 64,
        WT_c2l + l * 4096, c2_bl + l * 64, A2, WT_c2r + l * 4096, c2_br + l * 64, B2);
    gat_gather2<<<gN4, blk, 0, stream>>>(rp1, eid1, src1s, attr,
        WEC + l * 1024, BEC + l * 64, c1_att + l * 64, c1_bias + l * 64,
        WEC + (3 + l) * 1024, BEC + (3 + l) * 64, c2_att + l * 64, c2_bias + l * 64,
        A, B, node_embed, Hc,
        A2, B2, F0, Fc, N);
  }

  // xf assembly
  xf_init<<<((long)S * 192 + 255) / 256, blk, 0, stream>>>(XF, seg_embed, time_embed, week_embed,
                                                           cur_t, cur_w, S);
  spmm_se_g<<<gS4, blk, 0, stream>>>(rp2, col2s, val2s, edge_embed, attr,
                                     attr2_W, attr2_b, XF, S);
  spmm_sn_g<<<gS4, blk, 0, stream>>>(rp3, col3s, val3s, Hc, Fc, XF, S);

  // conv3 on segment graph (K=448), bf16 xl3/xr3
  gemm_mfma<0, true, false, true><<<gS64, blk, 0, stream>>>(XF, S, 448, WT_c3l, c3_bl, A,
                                                            WT_c3r, c3_br, B);
  gat_seg_g<<<gS4, blk, 0, stream>>>(rp4, src4s, val4s, c3_We, c3_att, c3_bias,
                                     A, B, XFG, S);

  // MLP head
  gemm_mfma<1, false, false, false><<<gS64, blk, 0, stream>>>(XF, S, 448, WT_lin1, lin1_b, Y,
                                                              nullptr, nullptr, nullptr);
  gemm_mfma<1, false, false, false><<<gS64, blk, 0, stream>>>(Y, S, 64, WT_lin2, lin2_b, Y2,
                                                              nullptr, nullptr, nullptr);
  head_k<<<gS4, blk, 0, stream>>>(Y2, XFG, out_W, out_b, (float*)d_out, S);
}